// Round 10
// baseline (685.854 us; speedup 1.0000x reference)
//
#include <hip/hip_runtime.h>
#include <hip/hip_fp16.h>
#include <math.h>

#define NN 50000
#define NE 600000
#define NT ((NN + 31) / 32)   // 1563 row-tiles of 32

// histogram degree-count params
#define HB 64        // histogram blocks
#define HBINS 12500  // bins per phase (50KB LDS); 4 ranges x {src,dst} = 8 phases
// placement params
#define PB 64
#define PRANGE ((NN + PB - 1) / PB)   // 782 nodes per placement block

typedef _Float16 half8_t __attribute__((ext_vector_type(8)));
typedef float f32x16 __attribute__((ext_vector_type(16)));
typedef float f32x2 __attribute__((ext_vector_type(2)));

union F2H { float2 f; __half2 h[2]; };

// fp8 e4m3 encode/decode via gfx950 HW cvt (verified pair)
__device__ __forceinline__ float fp8_dec1(unsigned int u) {
  f32x2 v = __builtin_amdgcn_cvt_pk_f32_fp8(u, false);
  return v.x;  // decodes byte 0
}
__device__ __forceinline__ unsigned char fp8_enc1(float a) {
  return (unsigned char)__builtin_amdgcn_cvt_pk_fp8_f32(a, a, 0u, false);
}

// Packed fragment layout for MFMA (32x32x16_f16):
//   element (row r in tile t, feature k): ks=k>>4, g=(k&15)>>3, j=k&7
//   halves index = ((t*8 + ks)*64 + g*32 + r)*8 + j   (per 128-k buffer)

// -- tanh -> fp16 (self/residual) + fp8*no (APPNP source) --------------------
__global__ __launch_bounds__(256) void k_tanh(const float* __restrict__ x,
                                              const float* __restrict__ no,
                                              __half2* __restrict__ x0h,
                                              unsigned int* __restrict__ x0n8) {
  int i = blockIdx.x * 256 + threadIdx.x;
  if (i >= NN * 32) return;
  float4 v = reinterpret_cast<const float4*>(x)[i];
  float t[4];
  float vv[4] = {v.x, v.y, v.z, v.w};
  #pragma unroll
  for (int j = 0; j < 4; ++j) {
    float xc = fminf(fmaxf(vv[j], -9.f), 9.f);
    float E = __expf(2.f * xc);
    t[j] = (E - 1.f) / (E + 1.f);
  }
  float s = no[i >> 5];  // 32 float4 per node row
  F2H a;
  a.h[0] = __floats2half2_rn(t[0], t[1]);
  a.h[1] = __floats2half2_rn(t[2], t[3]);
  reinterpret_cast<float2*>(x0h)[i] = a.f;
  unsigned int p = __builtin_amdgcn_cvt_pk_fp8_f32(t[0] * s, t[1] * s, 0u, false);
  p = __builtin_amdgcn_cvt_pk_fp8_f32(t[2] * s, t[3] * s, p, true);
  x0n8[i] = p;
}

// ------------- W transpose -> fragment-packed fp16 (runs once, tiny) --------
__global__ __launch_bounds__(256) void k_wt(const float* __restrict__ W1,
                                            const float* __restrict__ W2,
                                            _Float16* __restrict__ w1p,
                                            _Float16* __restrict__ w2p) {
  int i = blockIdx.x * 256 + threadIdx.x;
  if (i < 128 * 128) {
    int k = i >> 7, n = i & 127;
    int nb = n >> 5, r = n & 31, ks = k >> 4, g = (k & 15) >> 3, j = k & 7;
    w1p[(((ks << 2) + nb) * 64 + (g << 5) + r) * 8 + j] = (_Float16)W1[i];
  } else {
    int q = i - 128 * 128;
    if (q < 256 * 128) {
      int k = q >> 7, n = q & 127;
      int nb = n >> 5, r = n & 31, ks = k >> 4, g = (k & 15) >> 3, j = k & 7;
      w2p[(((ks << 2) + nb) * 64 + (g << 5) + r) * 8 + j] = (_Float16)W2[q];
    }
  }
}

// ---- degree count via LDS-privatized histogram (no global atomics) --------
__global__ __launch_bounds__(1024) void k_hist(const int* __restrict__ src,
                                               const int* __restrict__ dst,
                                               int* __restrict__ hpart) {
  __shared__ int lh[HBINS];
  #pragma unroll 1
  for (int ph = 0; ph < 8; ++ph) {
    const int* idx = (ph & 4) ? dst : src;
    int base = (ph & 3) * HBINS;
    for (int i = threadIdx.x; i < HBINS; i += 1024) lh[i] = 0;
    __syncthreads();
    for (int e = blockIdx.x * 1024 + threadIdx.x; e < NE; e += HB * 1024) {
      int v = idx[e] - base;
      if ((unsigned)v < (unsigned)HBINS) atomicAdd(&lh[v], 1);
    }
    __syncthreads();
    int* outp = hpart + ((size_t)ph * HB + blockIdx.x) * HBINS;
    for (int i = threadIdx.x; i < HBINS; i += 1024) outp[i] = lh[i];
    __syncthreads();
  }
}

// ---- merge partials -> in-degree (for scan) + both norms -------------------
__global__ __launch_bounds__(256) void k_merge(const int* __restrict__ hpart,
                                               int* __restrict__ ci,
                                               float* __restrict__ no,
                                               float* __restrict__ ni) {
  int i = blockIdx.x * 256 + threadIdx.x;
  if (i >= NN) return;
  int r = i / HBINS, bin = i - r * HBINS;
  const int* ps = hpart + ((size_t)(0 + r) * HB) * HBINS + bin;      // src phases 0..3
  const int* pd = hpart + ((size_t)(4 + r) * HB) * HBINS + bin;      // dst phases 4..7
  int so = 0, si = 0;
  #pragma unroll 8
  for (int b = 0; b < HB; ++b) {
    so += ps[(size_t)b * HBINS];
    si += pd[(size_t)b * HBINS];
  }
  ci[i] = si;
  no[i] = rsqrtf((float)max(so, 1));
  ni[i] = rsqrtf((float)max(si, 1));
}

// ---------------- exclusive scan of in-degrees ----------------
__global__ __launch_bounds__(1024) void k_scanA(const int* __restrict__ deg,
                                                int* __restrict__ incl,
                                                int* __restrict__ bsum) {
  int tid = threadIdx.x;
  int gid = blockIdx.x * 1024 + tid;
  int v = (gid < NN) ? deg[gid] : 0;
  int lane = tid & 63;
  #pragma unroll
  for (int o = 1; o < 64; o <<= 1) {
    int n = __shfl_up(v, o);
    if (lane >= o) v += n;
  }
  __shared__ int ws[16];
  int wid = tid >> 6;
  if (lane == 63) ws[wid] = v;
  __syncthreads();
  if (tid < 16) {
    int s = ws[tid];
    #pragma unroll
    for (int o = 1; o < 16; o <<= 1) {
      int n = __shfl_up(s, o);
      if (tid >= o) s += n;
    }
    ws[tid] = s;
  }
  __syncthreads();
  if (wid > 0) v += ws[wid - 1];
  if (gid < NN) incl[gid] = v;
  if (tid == 1023) bsum[blockIdx.x] = v;
}

__global__ __launch_bounds__(64) void k_scanB(const int* __restrict__ bsum,
                                              int* __restrict__ boff, int nb) {
  int t = threadIdx.x;
  int v = (t < nb) ? bsum[t] : 0;
  int orig = v;
  #pragma unroll
  for (int o = 1; o < 64; o <<= 1) {
    int n = __shfl_up(v, o);
    if (t >= o) v += n;
  }
  if (t < nb) boff[t] = v - orig;  // exclusive
}

__global__ __launch_bounds__(256) void k_scanC(const int* __restrict__ incl,
                                               const int* __restrict__ deg,
                                               const int* __restrict__ boff,
                                               int* __restrict__ rp) {
  int i = blockIdx.x * 256 + threadIdx.x;
  if (i < NN) rp[i] = incl[i] - deg[i] + boff[i >> 10];
  if (i == 0) rp[NN] = NE;
}

// ---- CSR placement via LDS slot counters (no global atomics) --------------
// Block b owns dst range [b*PRANGE, ...); scans all edges coalesced.
__global__ __launch_bounds__(1024) void k_place(const int* __restrict__ src,
                                                const int* __restrict__ dst,
                                                const int* __restrict__ rp,
                                                int* __restrict__ colsrc) {
  __shared__ int lc[PRANGE];
  int base = blockIdx.x * PRANGE;
  int lim = NN - base; if (lim > PRANGE) lim = PRANGE;
  for (int i = threadIdx.x; i < PRANGE; i += 1024) lc[i] = 0;
  __syncthreads();
  for (int e = threadIdx.x; e < NE; e += 1024) {
    int d = dst[e] - base;
    if ((unsigned)d < (unsigned)lim) {
      int pos = rp[base + d] + atomicAdd(&lc[d], 1);
      colsrc[pos] = src[e];
    }
  }
}

#define GATHER_LOOP(LOADEXPR)                                        \
  for (int base = 0; base < cnt; base += 64) {                      \
    int e = beg + base + lane;                                      \
    int cv = (e < end) ? cs[e] : 0;                                 \
    int m = cnt - base; if (m > 64) m = 64;                         \
    int j = 0;                                                      \
    for (; j + 8 <= m; j += 8) {                                    \
      _Pragma("unroll")                                             \
      for (int u = 0; u < 8; ++u) {                                 \
        int s = __builtin_amdgcn_readlane(cv, j + u);               \
        LOADEXPR;                                                   \
      }                                                             \
    }                                                               \
    for (; j < m; ++j) {                                            \
      int s = __builtin_amdgcn_readlane(cv, j);                     \
      LOADEXPR;                                                     \
    }                                                               \
  }

// ---- APPNP iteration, XCD-pinned feature-half split ------------------------
// Wave = (node w, half hf); hf = (blockIdx>>2)&1 so halves pin to XCD groups
// under %8 round-robin block->XCD mapping: per-L2 working set 3.2 MB (fits).
// Lane = one feature: 1B fp8 load per edge (one 64B line per edge per wave).
// LAST=false: out fp8 scaled by no. LAST=true: out fp16 unscaled (h5).
template <bool LAST>
__global__ __launch_bounds__(256) void k_appnp8s(const unsigned char* __restrict__ h8,
                                                 const __half* __restrict__ x0,
                                                 const float* __restrict__ no,
                                                 const float* __restrict__ ni,
                                                 const int* __restrict__ rp,
                                                 const int* __restrict__ cs,
                                                 unsigned char* __restrict__ out8,
                                                 __half* __restrict__ out16) {
  int bid = blockIdx.x;
  int hf = (bid >> 2) & 1;
  int grp = (bid >> 3) * 4 + (bid & 3);  // [0, 12500)
  int w = grp * 4 + (threadIdx.x >> 6);
  int lane = threadIdx.x & 63;
  if (w >= NN) return;
  const unsigned char* hl = h8 + hf * 64 + lane;
  int beg = rp[w], end = rp[w + 1], cnt = end - beg;
  float a = 0.f;
  GATHER_LOOP({
    unsigned int uv = hl[(size_t)s * 128];
    a += fp8_dec1(uv);
  })
  float wi = 0.8f * ni[w];
  float xv = __half2float(x0[(size_t)w * 128 + hf * 64 + lane]);
  float r = wi * a + 0.2f * xv;
  if (LAST) {
    out16[(size_t)w * 128 + hf * 64 + lane] = __float2half(r);
  } else {
    out8[(size_t)w * 128 + hf * 64 + lane] = fp8_enc1(r * no[w]);
  }
}

// packed-store helper: thread (node w, lane) holds features (2*lane, 2*lane+1)
__device__ inline void store_packed(_Float16* __restrict__ zp, int w, int lane,
                                    float v0, float v1) {
  int t = w >> 5, r = w & 31;
  int ks = lane >> 3, g = (lane >> 2) & 1, j = (lane & 3) * 2;
  size_t addr = (((size_t)t * 8 + ks) * 64 + g * 32 + r) * 8 + j;
  *reinterpret_cast<__half2*>(zp + addr) = __floats2half2_rn(v0, v1);
}

// ---- gather + GIN affine, packed out: z = (1+eps)*h[w] + sum(h[s]) ---------
__global__ __launch_bounds__(256) void k_gather_z(const __half2* __restrict__ h,
                                                  const float* __restrict__ epsp,
                                                  const int* __restrict__ rp,
                                                  const int* __restrict__ cs,
                                                  _Float16* __restrict__ zout) {
  int w = (blockIdx.x * 256 + threadIdx.x) >> 6;
  int lane = threadIdx.x & 63;
  if (w >= NN) return;
  const __half2* hl = h + lane;
  int beg = rp[w], end = rp[w + 1], cnt = end - beg;
  float ax = 0.f, ay = 0.f;
  GATHER_LOOP({
    float2 f = __half22float2(hl[s * 64]);
    ax += f.x; ay += f.y;
  })
  float e1 = 1.0f + epsp[0];
  float2 hv = __half22float2(h[w * 64 + lane]);
  store_packed(zout, w, lane, e1 * hv.x + ax, e1 * hv.y + ay);
}

// ---- MFMA GEMM on packed operands: C = Z @ W + b -------------------------
template <int KTOT, bool MISH>
__global__ __launch_bounds__(64) void k_mgemm(const _Float16* __restrict__ z0,
                                              const _Float16* __restrict__ z1,
                                              const _Float16* __restrict__ wp,
                                              const float* __restrict__ bias,
                                              float* __restrict__ outf,
                                              __half2* __restrict__ outh) {
  int lane = threadIdx.x;
  int t = blockIdx.x;
  int row0 = t * 32;
  if (row0 >= NN) return;
  int r31 = lane & 31, g = lane >> 5;
  f32x16 acc[4];
  #pragma unroll
  for (int i = 0; i < 4; ++i) acc[i] = (f32x16)(0.0f);
  #pragma unroll 4
  for (int ks = 0; ks < KTOT / 16; ++ks) {
    const _Float16* zp = (KTOT == 256 && ks >= 8) ? z1 : z0;
    int kls = (KTOT == 256) ? (ks & 7) : ks;
    half8_t a = *reinterpret_cast<const half8_t*>(
        zp + (((size_t)t * 8 + kls) * 64 + lane) * 8);
    #pragma unroll
    for (int nb = 0; nb < 4; ++nb) {
      half8_t b = *reinterpret_cast<const half8_t*>(
          wp + (((size_t)ks * 4 + nb) * 64 + lane) * 8);
      acc[nb] = __builtin_amdgcn_mfma_f32_32x32x16_f16(a, b, acc[nb], 0, 0, 0);
    }
  }
  #pragma unroll
  for (int nb = 0; nb < 4; ++nb) {
    float bv = bias[nb * 32 + r31];
    #pragma unroll
    for (int r = 0; r < 16; ++r) {
      int rl = (r & 3) + 8 * (r >> 2) + 4 * g;
      int grow = row0 + rl;
      if (grow < NN) {
        float v = acc[nb][r] + bv;
        if (MISH) {
          // mish(v) = v*q/(q+2), q = E(E+2), E = e^v
          float E = __expf(v);
          float q = E * (E + 2.f);
          float mv = v * q / (q + 2.f);
          v = (v > 15.f) ? v : mv;
          outf[(size_t)grow * 128 + nb * 32 + r31] = v;
        } else {
          float u = __shfl_xor(v, 1);
          if (!(lane & 1)) {
            outh[((size_t)grow * 128 + nb * 32 + r31) >> 1] = __floats2half2_rn(v, u);
          }
        }
      }
    }
  }
}

extern "C" void kernel_launch(void* const* d_in, const int* in_sizes, int n_in,
                              void* d_out, int out_size, void* d_ws, size_t ws_size,
                              hipStream_t stream) {
  const float* x = (const float*)d_in[0];
  const int* src = (const int*)d_in[1];
  const int* dst = (const int*)d_in[2];
  const float* W1 = (const float*)d_in[3];
  const float* b1 = (const float*)d_in[4];
  const float* W2 = (const float*)d_in[5];
  const float* b2 = (const float*)d_in[6];
  const float* eps1 = (const float*)d_in[7];
  const float* eps2 = (const float*)d_in[8];
  float* out = (float*)d_out;

  char* ws = (char*)d_ws;
  size_t off = 0;
  auto alloc = [&](size_t bytes) -> void* {
    void* p = ws + off;
    off += (bytes + 255) & ~(size_t)255;
    return p;
  };
  const size_t NDP = (size_t)NT * 4096;  // halves per padded fp16 buffer
  __half2* x0h = (__half2*)alloc(NDP * 2);             // tanh(x), fp16
  unsigned char* x0n8 = (unsigned char*)alloc(NDP);    // fp8 tanh(x)*no
  unsigned char* hA8 = (unsigned char*)alloc(NDP);     // fp8 APPNP ping
  unsigned char* hB8 = (unsigned char*)alloc(NDP);     // fp8 APPNP pong
  __half2* h5 = (__half2*)alloc(NDP * 2);              // fp16 APPNP output
  __half2* zx = (__half2*)alloc(NDP * 2);              // packed (1+e2)*x0+agg(x0)
  __half2* z1p = (__half2*)alloc(NDP * 2);             // packed (1+e1)*h5+agg(h5)
  __half2* g1h = (__half2*)alloc(NDP * 2);             // GIN1 out, fp16
  __half2* zg = (__half2*)alloc(NDP * 2);              // packed (1+e2)*g1+agg(g1)
  _Float16* w1p = (_Float16*)alloc(128 * 128 * 2);
  _Float16* w2p = (_Float16*)alloc(256 * 128 * 2);
  int* ci = (int*)alloc(NN * 4);
  float* nrm_o = (float*)alloc(NN * 4);
  float* nrm_i = (float*)alloc(NN * 4);
  int* incl = (int*)alloc(NN * 4);
  int* bsum = (int*)alloc(64 * 4);
  int* boff = (int*)alloc(64 * 4);
  int* rp = (int*)alloc((NN + 1) * 4);
  int* colsrc = (int*)alloc(NE * 4);

  // histogram partials: 8 phases x HB blocks x HBINS x 4B = 25.6 MB.
  // Aliased over zx+z1p: those are first written after k_merge consumed them.
  int* hpart = (int*)zx;

  // degrees via LDS histogram, then norms + scan + LDS-slot CSR placement
  k_hist<<<HB, 1024, 0, stream>>>(src, dst, hpart);
  k_merge<<<(NN + 255) / 256, 256, 0, stream>>>(hpart, ci, nrm_o, nrm_i);

  const int SB = (NN + 1023) / 1024;  // 49
  k_scanA<<<SB, 1024, 0, stream>>>(ci, incl, bsum);
  k_scanB<<<1, 64, 0, stream>>>(bsum, boff, SB);
  k_scanC<<<(NN + 255) / 256, 256, 0, stream>>>(incl, ci, boff, rp);
  k_place<<<PB, 1024, 0, stream>>>(src, dst, rp, colsrc);

  k_tanh<<<(NN * 32 + 255) / 256, 256, 0, stream>>>(x, nrm_o, x0h,
                                                    (unsigned int*)x0n8);
  k_wt<<<192, 256, 0, stream>>>(W1, W2, w1p, w2p);

  const __half* x0hs = (const __half*)x0h;
  const int AB = 25000;  // 2 halves x 12500 node-groups of 4 waves
  // APPNP iters 1..5 (fp8 XCD-split), 5th emits fp16 h5
  k_appnp8s<false><<<AB, 256, 0, stream>>>(x0n8, x0hs, nrm_o, nrm_i, rp, colsrc,
                                           hA8, nullptr);
  k_appnp8s<false><<<AB, 256, 0, stream>>>(hA8, x0hs, nrm_o, nrm_i, rp, colsrc,
                                           hB8, nullptr);
  k_appnp8s<false><<<AB, 256, 0, stream>>>(hB8, x0hs, nrm_o, nrm_i, rp, colsrc,
                                           hA8, nullptr);
  k_appnp8s<false><<<AB, 256, 0, stream>>>(hA8, x0hs, nrm_o, nrm_i, rp, colsrc,
                                           hB8, nullptr);
  k_appnp8s<true><<<AB, 256, 0, stream>>>(hB8, x0hs, nrm_o, nrm_i, rp, colsrc,
                                          nullptr, (__half*)h5);

  const int GB = (NN * 64 + 255) / 256;  // one wave per node
  // zx(packed) = (1+eps2)*x0 + agg(x0)   [fp16]
  k_gather_z<<<GB, 256, 0, stream>>>(x0h, eps2, rp, colsrc, (_Float16*)zx);
  // z1(packed) = (1+eps1)*h5 + agg(h5)   [fp16]
  k_gather_z<<<GB, 256, 0, stream>>>(h5, eps1, rp, colsrc, (_Float16*)z1p);

  // GIN1: g1 = z1 @ W1 + b1 -> fp16 row-major
  k_mgemm<128, false><<<NT, 64, 0, stream>>>((const _Float16*)z1p, nullptr, w1p, b1,
                                             nullptr, g1h);
  // zg(packed) = (1+eps2)*g1 + agg(g1)   [fp16]
  k_gather_z<<<GB, 256, 0, stream>>>(g1h, eps2, rp, colsrc, (_Float16*)zg);
  // GIN2: out = mish([zg | zx] @ W2 + b2)
  k_mgemm<256, true><<<NT, 64, 0, stream>>>((const _Float16*)zg, (const _Float16*)zx,
                                            w2p, b2, out, nullptr);
}

// Round 11
// 309.840 us; speedup vs baseline: 2.2136x; 2.2136x over previous
//
#include <hip/hip_runtime.h>
#include <hip/hip_fp16.h>
#include <math.h>

#define NN 50000
#define NE 600000
#define NT ((NN + 31) / 32)   // 1563 row-tiles of 32

// histogram degree-count params
#define HB 64        // histogram blocks
#define HBINS 12500  // bins per phase (50KB LDS); 4 ranges x {src,dst} = 8 phases

typedef _Float16 half8_t __attribute__((ext_vector_type(8)));
typedef float f32x16 __attribute__((ext_vector_type(16)));
typedef float f32x2 __attribute__((ext_vector_type(2)));

union F2H { float2 f; __half2 h[2]; };

// fp8 e4m3 encode/decode via gfx950 HW cvt (self-consistent pair)
__device__ __forceinline__ float2 fp8_dec(unsigned short u) {
  f32x2 v = __builtin_amdgcn_cvt_pk_f32_fp8((unsigned int)u, false);
  float2 r; r.x = v.x; r.y = v.y; return r;
}
__device__ __forceinline__ unsigned short fp8_enc(float a, float b) {
  return (unsigned short)__builtin_amdgcn_cvt_pk_fp8_f32(a, b, 0u, false);
}

// Packed fragment layout for MFMA (32x32x16_f16):
//   element (row r in tile t, feature k): ks=k>>4, g=(k&15)>>3, j=k&7
//   halves index = ((t*8 + ks)*64 + g*32 + r)*8 + j   (per 128-k buffer)

// -- tanh -> fp16 (self/residual) + fp8*no (APPNP source) --------------------
__global__ __launch_bounds__(256) void k_tanh(const float* __restrict__ x,
                                              const float* __restrict__ no,
                                              __half2* __restrict__ x0h,
                                              unsigned int* __restrict__ x0n8) {
  int i = blockIdx.x * 256 + threadIdx.x;
  if (i >= NN * 32) return;
  float4 v = reinterpret_cast<const float4*>(x)[i];
  float t[4];
  float vv[4] = {v.x, v.y, v.z, v.w};
  #pragma unroll
  for (int j = 0; j < 4; ++j) {
    float xc = fminf(fmaxf(vv[j], -9.f), 9.f);
    float E = __expf(2.f * xc);
    t[j] = (E - 1.f) / (E + 1.f);
  }
  float s = no[i >> 5];  // 32 float4 per node row
  F2H a;
  a.h[0] = __floats2half2_rn(t[0], t[1]);
  a.h[1] = __floats2half2_rn(t[2], t[3]);
  reinterpret_cast<float2*>(x0h)[i] = a.f;
  unsigned int p = __builtin_amdgcn_cvt_pk_fp8_f32(t[0] * s, t[1] * s, 0u, false);
  p = __builtin_amdgcn_cvt_pk_fp8_f32(t[2] * s, t[3] * s, p, true);
  x0n8[i] = p;
}

// ------------- W transpose -> fragment-packed fp16 (runs once, tiny) --------
__global__ __launch_bounds__(256) void k_wt(const float* __restrict__ W1,
                                            const float* __restrict__ W2,
                                            _Float16* __restrict__ w1p,
                                            _Float16* __restrict__ w2p) {
  int i = blockIdx.x * 256 + threadIdx.x;
  if (i < 128 * 128) {
    int k = i >> 7, n = i & 127;
    int nb = n >> 5, r = n & 31, ks = k >> 4, g = (k & 15) >> 3, j = k & 7;
    w1p[(((ks << 2) + nb) * 64 + (g << 5) + r) * 8 + j] = (_Float16)W1[i];
  } else {
    int q = i - 128 * 128;
    if (q < 256 * 128) {
      int k = q >> 7, n = q & 127;
      int nb = n >> 5, r = n & 31, ks = k >> 4, g = (k & 15) >> 3, j = k & 7;
      w2p[(((ks << 2) + nb) * 64 + (g << 5) + r) * 8 + j] = (_Float16)W2[q];
    }
  }
}

// ---- degree count via LDS-privatized histogram (no global atomics) --------
__global__ __launch_bounds__(1024) void k_hist(const int* __restrict__ src,
                                               const int* __restrict__ dst,
                                               int* __restrict__ hpart) {
  __shared__ int lh[HBINS];
  #pragma unroll 1
  for (int ph = 0; ph < 8; ++ph) {
    const int* idx = (ph & 4) ? dst : src;
    int base = (ph & 3) * HBINS;
    for (int i = threadIdx.x; i < HBINS; i += 1024) lh[i] = 0;
    __syncthreads();
    for (int e = blockIdx.x * 1024 + threadIdx.x; e < NE; e += HB * 1024) {
      int v = idx[e] - base;
      if ((unsigned)v < (unsigned)HBINS) atomicAdd(&lh[v], 1);
    }
    __syncthreads();
    int* outp = hpart + ((size_t)ph * HB + blockIdx.x) * HBINS;
    for (int i = threadIdx.x; i < HBINS; i += 1024) outp[i] = lh[i];
    __syncthreads();
  }
}

// ---- merge partials -> in-degree (for scan) + both norms -------------------
__global__ __launch_bounds__(256) void k_merge(const int* __restrict__ hpart,
                                               int* __restrict__ ci,
                                               float* __restrict__ no,
                                               float* __restrict__ ni) {
  int i = blockIdx.x * 256 + threadIdx.x;
  if (i >= NN) return;
  int r = i / HBINS, bin = i - r * HBINS;
  const int* ps = hpart + ((size_t)(0 + r) * HB) * HBINS + bin;      // src phases 0..3
  const int* pd = hpart + ((size_t)(4 + r) * HB) * HBINS + bin;      // dst phases 4..7
  int so = 0, si = 0;
  #pragma unroll 8
  for (int b = 0; b < HB; ++b) {
    so += ps[(size_t)b * HBINS];
    si += pd[(size_t)b * HBINS];
  }
  ci[i] = si;
  no[i] = rsqrtf((float)max(so, 1));
  ni[i] = rsqrtf((float)max(si, 1));
}

// ---------------- exclusive scan of in-degrees ----------------
__global__ __launch_bounds__(1024) void k_scanA(const int* __restrict__ deg,
                                                int* __restrict__ incl,
                                                int* __restrict__ bsum) {
  int tid = threadIdx.x;
  int gid = blockIdx.x * 1024 + tid;
  int v = (gid < NN) ? deg[gid] : 0;
  int lane = tid & 63;
  #pragma unroll
  for (int o = 1; o < 64; o <<= 1) {
    int n = __shfl_up(v, o);
    if (lane >= o) v += n;
  }
  __shared__ int ws[16];
  int wid = tid >> 6;
  if (lane == 63) ws[wid] = v;
  __syncthreads();
  if (tid < 16) {
    int s = ws[tid];
    #pragma unroll
    for (int o = 1; o < 16; o <<= 1) {
      int n = __shfl_up(s, o);
      if (tid >= o) s += n;
    }
    ws[tid] = s;
  }
  __syncthreads();
  if (wid > 0) v += ws[wid - 1];
  if (gid < NN) incl[gid] = v;
  if (tid == 1023) bsum[blockIdx.x] = v;
}

__global__ __launch_bounds__(64) void k_scanB(const int* __restrict__ bsum,
                                              int* __restrict__ boff, int nb) {
  int t = threadIdx.x;
  int v = (t < nb) ? bsum[t] : 0;
  int orig = v;
  #pragma unroll
  for (int o = 1; o < 64; o <<= 1) {
    int n = __shfl_up(v, o);
    if (t >= o) v += n;
  }
  if (t < nb) boff[t] = v - orig;  // exclusive
}

__global__ __launch_bounds__(256) void k_scanC(const int* __restrict__ incl,
                                               const int* __restrict__ deg,
                                               const int* __restrict__ boff,
                                               int* __restrict__ rp) {
  int i = blockIdx.x * 256 + threadIdx.x;
  if (i < NN) rp[i] = incl[i] - deg[i] + boff[i >> 10];
  if (i == 0) rp[NN] = NE;
}

// ---------------- CSR bucket fill ----------------
__global__ __launch_bounds__(256) void k_fill(const int* __restrict__ src,
                                              const int* __restrict__ dst,
                                              const int* __restrict__ rp,
                                              int* __restrict__ fill,
                                              int* __restrict__ colsrc) {
  int e = blockIdx.x * 256 + threadIdx.x;
  if (e < NE) {
    int d = dst[e];
    int pos = rp[d] + atomicAdd(&fill[d], 1);
    colsrc[pos] = src[e];
  }
}

// Edge loop with cascade tail (8/4/2/1): independent loads batched at every
// tail size — gathers are issue/latency-bound, serial singles were the cost.
#define GATHER_LOOP(LOADEXPR)                                        \
  for (int base = 0; base < cnt; base += 64) {                      \
    int e = beg + base + lane;                                      \
    int cv = (e < end) ? cs[e] : 0;                                 \
    int m = cnt - base; if (m > 64) m = 64;                         \
    int j = 0;                                                      \
    for (; j + 8 <= m; j += 8) {                                    \
      _Pragma("unroll")                                             \
      for (int u = 0; u < 8; ++u) {                                 \
        int s = __builtin_amdgcn_readlane(cv, j + u);               \
        LOADEXPR;                                                   \
      }                                                             \
    }                                                               \
    if (j + 4 <= m) {                                               \
      _Pragma("unroll")                                             \
      for (int u = 0; u < 4; ++u) {                                 \
        int s = __builtin_amdgcn_readlane(cv, j + u);               \
        LOADEXPR;                                                   \
      }                                                             \
      j += 4;                                                       \
    }                                                               \
    if (j + 2 <= m) {                                               \
      _Pragma("unroll")                                             \
      for (int u = 0; u < 2; ++u) {                                 \
        int s = __builtin_amdgcn_readlane(cv, j + u);               \
        LOADEXPR;                                                   \
      }                                                             \
      j += 2;                                                       \
    }                                                               \
    if (j < m) {                                                    \
      int s = __builtin_amdgcn_readlane(cv, j);                     \
      LOADEXPR;                                                     \
    }                                                               \
  }

// ---- APPNP iteration (fp8 source): r = 0.8*ni*sum(h8[s]) + 0.2*x0 ----------
// LAST=false: write fp8 scaled by no (next iteration's source).
// LAST=true:  write fp16 unscaled (h5).
template <bool LAST>
__global__ __launch_bounds__(256) void k_appnp8(const unsigned short* __restrict__ h8,
                                                const __half2* __restrict__ x0,
                                                const float* __restrict__ no,
                                                const float* __restrict__ ni,
                                                const int* __restrict__ rp,
                                                const int* __restrict__ cs,
                                                unsigned short* __restrict__ out8,
                                                __half2* __restrict__ out16) {
  int w = (blockIdx.x * 256 + threadIdx.x) >> 6;
  int lane = threadIdx.x & 63;
  if (w >= NN) return;
  const unsigned short* hl = h8 + lane;
  int beg = rp[w], end = rp[w + 1], cnt = end - beg;
  float ax = 0.f, ay = 0.f;
  GATHER_LOOP({
    float2 f = fp8_dec(hl[s * 64]);
    ax += f.x; ay += f.y;
  })
  float wi = 0.8f * ni[w];
  float2 xv = __half22float2(x0[w * 64 + lane]);
  float rx = wi * ax + 0.2f * xv.x;
  float ry = wi * ay + 0.2f * xv.y;
  if (LAST) {
    out16[w * 64 + lane] = __floats2half2_rn(rx, ry);
  } else {
    float sc = no[w];
    out8[w * 64 + lane] = fp8_enc(rx * sc, ry * sc);
  }
}

// packed-store helper: thread (node w, lane) holds features (2*lane, 2*lane+1)
__device__ inline void store_packed(_Float16* __restrict__ zp, int w, int lane,
                                    float v0, float v1) {
  int t = w >> 5, r = w & 31;
  int ks = lane >> 3, g = (lane >> 2) & 1, j = (lane & 3) * 2;
  size_t addr = (((size_t)t * 8 + ks) * 64 + g * 32 + r) * 8 + j;
  *reinterpret_cast<__half2*>(zp + addr) = __floats2half2_rn(v0, v1);
}

// ---- first APPNP pass fused with agg(x0): dual gather (x0*no fp8, x0 fp16) -
// hout8 = fp8( no*(0.8*ni*sum(x0n8[s]) + 0.2*x0[w]) )
// zout(packed fp16) = (1+eps2)*x0[w] + sum(x0[s])
__global__ __launch_bounds__(256) void k_appnp_first(const unsigned short* __restrict__ xs8,
                                                     const __half2* __restrict__ xp,
                                                     const float* __restrict__ epsp,
                                                     const float* __restrict__ no,
                                                     const float* __restrict__ ni,
                                                     const int* __restrict__ rp,
                                                     const int* __restrict__ cs,
                                                     unsigned short* __restrict__ hout8,
                                                     _Float16* __restrict__ zout) {
  int w = (blockIdx.x * 256 + threadIdx.x) >> 6;
  int lane = threadIdx.x & 63;
  if (w >= NN) return;
  const unsigned short* xsl = xs8 + lane;
  const __half2* xpl = xp + lane;
  int beg = rp[w], end = rp[w + 1], cnt = end - beg;
  float ax = 0.f, ay = 0.f, bx = 0.f, by = 0.f;
  GATHER_LOOP({
    float2 f = fp8_dec(xsl[s * 64]);
    float2 g2 = __half22float2(xpl[s * 64]);
    ax += f.x; ay += f.y; bx += g2.x; by += g2.y;
  })
  float2 xv = __half22float2(xp[w * 64 + lane]);
  float wi = 0.8f * ni[w];
  float sc = no[w];
  hout8[w * 64 + lane] = fp8_enc(sc * (wi * ax + 0.2f * xv.x),
                                 sc * (wi * ay + 0.2f * xv.y));
  float e2 = 1.0f + epsp[0];
  store_packed(zout, w, lane, e2 * xv.x + bx, e2 * xv.y + by);
}

// ---- gather + GIN affine, packed out: z = (1+eps)*h[w] + sum(h[s]) ---------
__global__ __launch_bounds__(256) void k_gather_z(const __half2* __restrict__ h,
                                                  const float* __restrict__ epsp,
                                                  const int* __restrict__ rp,
                                                  const int* __restrict__ cs,
                                                  _Float16* __restrict__ zout) {
  int w = (blockIdx.x * 256 + threadIdx.x) >> 6;
  int lane = threadIdx.x & 63;
  if (w >= NN) return;
  const __half2* hl = h + lane;
  int beg = rp[w], end = rp[w + 1], cnt = end - beg;
  float ax = 0.f, ay = 0.f;
  GATHER_LOOP({
    float2 f = __half22float2(hl[s * 64]);
    ax += f.x; ay += f.y;
  })
  float e1 = 1.0f + epsp[0];
  float2 hv = __half22float2(h[w * 64 + lane]);
  store_packed(zout, w, lane, e1 * hv.x + ax, e1 * hv.y + ay);
}

// ---- MFMA GEMM on packed operands: C = Z @ W + b -------------------------
template <int KTOT, bool MISH>
__global__ __launch_bounds__(64) void k_mgemm(const _Float16* __restrict__ z0,
                                              const _Float16* __restrict__ z1,
                                              const _Float16* __restrict__ wp,
                                              const float* __restrict__ bias,
                                              float* __restrict__ outf,
                                              __half2* __restrict__ outh) {
  int lane = threadIdx.x;
  int t = blockIdx.x;
  int row0 = t * 32;
  if (row0 >= NN) return;
  int r31 = lane & 31, g = lane >> 5;
  f32x16 acc[4];
  #pragma unroll
  for (int i = 0; i < 4; ++i) acc[i] = (f32x16)(0.0f);
  #pragma unroll 4
  for (int ks = 0; ks < KTOT / 16; ++ks) {
    const _Float16* zp = (KTOT == 256 && ks >= 8) ? z1 : z0;
    int kls = (KTOT == 256) ? (ks & 7) : ks;
    half8_t a = *reinterpret_cast<const half8_t*>(
        zp + (((size_t)t * 8 + kls) * 64 + lane) * 8);
    #pragma unroll
    for (int nb = 0; nb < 4; ++nb) {
      half8_t b = *reinterpret_cast<const half8_t*>(
          wp + (((size_t)ks * 4 + nb) * 64 + lane) * 8);
      acc[nb] = __builtin_amdgcn_mfma_f32_32x32x16_f16(a, b, acc[nb], 0, 0, 0);
    }
  }
  #pragma unroll
  for (int nb = 0; nb < 4; ++nb) {
    float bv = bias[nb * 32 + r31];
    #pragma unroll
    for (int r = 0; r < 16; ++r) {
      int rl = (r & 3) + 8 * (r >> 2) + 4 * g;
      int grow = row0 + rl;
      if (grow < NN) {
        float v = acc[nb][r] + bv;
        if (MISH) {
          // mish(v) = v*q/(q+2), q = E(E+2), E = e^v
          float E = __expf(v);
          float q = E * (E + 2.f);
          float mv = v * q / (q + 2.f);
          v = (v > 15.f) ? v : mv;
          outf[(size_t)grow * 128 + nb * 32 + r31] = v;
        } else {
          float u = __shfl_xor(v, 1);
          if (!(lane & 1)) {
            outh[((size_t)grow * 128 + nb * 32 + r31) >> 1] = __floats2half2_rn(v, u);
          }
        }
      }
    }
  }
}

extern "C" void kernel_launch(void* const* d_in, const int* in_sizes, int n_in,
                              void* d_out, int out_size, void* d_ws, size_t ws_size,
                              hipStream_t stream) {
  const float* x = (const float*)d_in[0];
  const int* src = (const int*)d_in[1];
  const int* dst = (const int*)d_in[2];
  const float* W1 = (const float*)d_in[3];
  const float* b1 = (const float*)d_in[4];
  const float* W2 = (const float*)d_in[5];
  const float* b2 = (const float*)d_in[6];
  const float* eps1 = (const float*)d_in[7];
  const float* eps2 = (const float*)d_in[8];
  float* out = (float*)d_out;

  char* ws = (char*)d_ws;
  size_t off = 0;
  auto alloc = [&](size_t bytes) -> void* {
    void* p = ws + off;
    off += (bytes + 255) & ~(size_t)255;
    return p;
  };
  const size_t NDP = (size_t)NT * 4096;  // halves per padded fp16 buffer
  __half2* x0h = (__half2*)alloc(NDP * 2);             // tanh(x), fp16
  unsigned short* x0n8 = (unsigned short*)alloc(NDP);  // fp8 tanh(x)*no
  unsigned short* hA8 = (unsigned short*)alloc(NDP);   // fp8 APPNP ping
  unsigned short* hB8 = (unsigned short*)alloc(NDP);   // fp8 APPNP pong
  __half2* h5 = (__half2*)alloc(NDP * 2);              // fp16 APPNP output
  __half2* zx = (__half2*)alloc(NDP * 2);              // packed (1+e2)*x0+agg(x0)
  __half2* z1p = (__half2*)alloc(NDP * 2);             // packed (1+e1)*h5+agg(h5)
  __half2* g1h = (__half2*)alloc(NDP * 2);             // GIN1 out, fp16
  __half2* zg = (__half2*)alloc(NDP * 2);              // packed (1+e2)*g1+agg(g1)
  _Float16* w1p = (_Float16*)alloc(128 * 128 * 2);
  _Float16* w2p = (_Float16*)alloc(256 * 128 * 2);
  int* ci = (int*)alloc(NN * 4);
  int* fillc = (int*)alloc(NN * 4);
  float* nrm_o = (float*)alloc(NN * 4);
  float* nrm_i = (float*)alloc(NN * 4);
  int* incl = (int*)alloc(NN * 4);
  int* bsum = (int*)alloc(64 * 4);
  int* boff = (int*)alloc(64 * 4);
  int* rp = (int*)alloc((NN + 1) * 4);
  int* colsrc = (int*)alloc(NE * 4);

  // histogram partials: 8 phases x HB blocks x HBINS x 4B = 25.6 MB.
  // Aliased over zx+z1p: those are first written after k_merge consumed them.
  int* hpart = (int*)zx;

  hipMemsetAsync(fillc, 0, NN * 4, stream);

  // degrees via LDS histogram (no global atomics), then norms + scan + CSR
  k_hist<<<HB, 1024, 0, stream>>>(src, dst, hpart);
  k_merge<<<(NN + 255) / 256, 256, 0, stream>>>(hpart, ci, nrm_o, nrm_i);

  const int SB = (NN + 1023) / 1024;  // 49
  k_scanA<<<SB, 1024, 0, stream>>>(ci, incl, bsum);
  k_scanB<<<1, 64, 0, stream>>>(bsum, boff, SB);
  k_scanC<<<(NN + 255) / 256, 256, 0, stream>>>(incl, ci, boff, rp);
  const int EB = (NE + 255) / 256;
  k_fill<<<EB, 256, 0, stream>>>(src, dst, rp, fillc, colsrc);

  k_tanh<<<(NN * 32 + 255) / 256, 256, 0, stream>>>(x, nrm_o, x0h,
                                                    (unsigned int*)x0n8);
  k_wt<<<192, 256, 0, stream>>>(W1, W2, w1p, w2p);

  const int GB = (NN * 64 + 255) / 256;  // one wave per node
  // APPNP iter1 fused with agg(x0): -> hA8 (fp8, scaled), zx (packed fp16)
  k_appnp_first<<<GB, 256, 0, stream>>>(x0n8, x0h, eps2, nrm_o, nrm_i, rp, colsrc,
                                        hA8, (_Float16*)zx);
  // APPNP iters 2..4 (fp8->fp8 scaled), iter 5 (fp8->fp16 unscaled)
  k_appnp8<false><<<GB, 256, 0, stream>>>(hA8, x0h, nrm_o, nrm_i, rp, colsrc,
                                          hB8, nullptr);
  k_appnp8<false><<<GB, 256, 0, stream>>>(hB8, x0h, nrm_o, nrm_i, rp, colsrc,
                                          hA8, nullptr);
  k_appnp8<false><<<GB, 256, 0, stream>>>(hA8, x0h, nrm_o, nrm_i, rp, colsrc,
                                          hB8, nullptr);
  k_appnp8<true><<<GB, 256, 0, stream>>>(hB8, x0h, nrm_o, nrm_i, rp, colsrc,
                                         nullptr, h5);

  // z1(packed) = (1+eps1)*h5 + agg(h5)   [fp16 source]
  k_gather_z<<<GB, 256, 0, stream>>>(h5, eps1, rp, colsrc, (_Float16*)z1p);

  // GIN1: g1 = z1 @ W1 + b1 -> fp16 row-major
  k_mgemm<128, false><<<NT, 64, 0, stream>>>((const _Float16*)z1p, nullptr, w1p, b1,
                                             nullptr, g1h);
  // zg(packed) = (1+eps2)*g1 + agg(g1)   [fp16 source]
  k_gather_z<<<GB, 256, 0, stream>>>(g1h, eps2, rp, colsrc, (_Float16*)zg);
  // GIN2: out = mish([zg | zx] @ W2 + b2)
  k_mgemm<256, true><<<NT, 64, 0, stream>>>((const _Float16*)zg, (const _Float16*)zx,
                                            w2p, b2, out, nullptr);
}

// Round 12
// 299.823 us; speedup vs baseline: 2.2875x; 1.0334x over previous
//
#include <hip/hip_runtime.h>
#include <hip/hip_fp16.h>
#include <math.h>

#define NN 50000
#define NE 600000
#define NT ((NN + 31) / 32)   // 1563 row-tiles of 32

// histogram degree-count params
#define HB 64        // histogram blocks
#define HBINS 12500  // bins per phase (50KB LDS); 4 ranges x {src,dst} = 8 phases

typedef _Float16 half8_t __attribute__((ext_vector_type(8)));
typedef float f32x16 __attribute__((ext_vector_type(16)));
typedef float f32x2 __attribute__((ext_vector_type(2)));

union F2H { float2 f; __half2 h[2]; };

// fp8 e4m3 encode/decode via gfx950 HW cvt (self-consistent pair)
__device__ __forceinline__ float2 fp8_dec(unsigned short u) {
  f32x2 v = __builtin_amdgcn_cvt_pk_f32_fp8((unsigned int)u, false);
  float2 r; r.x = v.x; r.y = v.y; return r;
}
__device__ __forceinline__ unsigned short fp8_enc(float a, float b) {
  return (unsigned short)__builtin_amdgcn_cvt_pk_fp8_f32(a, b, 0u, false);
}

// Packed fragment layout for MFMA (32x32x16_f16):
//   element (row r in tile t, feature k): ks=k>>4, g=(k&15)>>3, j=k&7
//   halves index = ((t*8 + ks)*64 + g*32 + r)*8 + j   (per 128-k buffer)

// -- tanh -> fp16 (self/residual) + fp8*no (APPNP source) --------------------
__global__ __launch_bounds__(256) void k_tanh(const float* __restrict__ x,
                                              const float* __restrict__ no,
                                              __half2* __restrict__ x0h,
                                              unsigned int* __restrict__ x0n8) {
  int i = blockIdx.x * 256 + threadIdx.x;
  if (i >= NN * 32) return;
  float4 v = reinterpret_cast<const float4*>(x)[i];
  float t[4];
  float vv[4] = {v.x, v.y, v.z, v.w};
  #pragma unroll
  for (int j = 0; j < 4; ++j) {
    float xc = fminf(fmaxf(vv[j], -9.f), 9.f);
    float E = __expf(2.f * xc);
    t[j] = (E - 1.f) / (E + 1.f);
  }
  float s = no[i >> 5];  // 32 float4 per node row
  F2H a;
  a.h[0] = __floats2half2_rn(t[0], t[1]);
  a.h[1] = __floats2half2_rn(t[2], t[3]);
  reinterpret_cast<float2*>(x0h)[i] = a.f;
  unsigned int p = __builtin_amdgcn_cvt_pk_fp8_f32(t[0] * s, t[1] * s, 0u, false);
  p = __builtin_amdgcn_cvt_pk_fp8_f32(t[2] * s, t[3] * s, p, true);
  x0n8[i] = p;
}

// ------------- W transpose -> fragment-packed fp16 (runs once, tiny) --------
__global__ __launch_bounds__(256) void k_wt(const float* __restrict__ W1,
                                            const float* __restrict__ W2,
                                            _Float16* __restrict__ w1p,
                                            _Float16* __restrict__ w2p) {
  int i = blockIdx.x * 256 + threadIdx.x;
  if (i < 128 * 128) {
    int k = i >> 7, n = i & 127;
    int nb = n >> 5, r = n & 31, ks = k >> 4, g = (k & 15) >> 3, j = k & 7;
    w1p[(((ks << 2) + nb) * 64 + (g << 5) + r) * 8 + j] = (_Float16)W1[i];
  } else {
    int q = i - 128 * 128;
    if (q < 256 * 128) {
      int k = q >> 7, n = q & 127;
      int nb = n >> 5, r = n & 31, ks = k >> 4, g = (k & 15) >> 3, j = k & 7;
      w2p[(((ks << 2) + nb) * 64 + (g << 5) + r) * 8 + j] = (_Float16)W2[q];
    }
  }
}

// ---- degree count via LDS-privatized histogram. dst phases additionally
// record each edge's within-(block,bin) sequence via returning LDS atomic. ----
__global__ __launch_bounds__(1024) void k_hist(const int* __restrict__ src,
                                               const int* __restrict__ dst,
                                               int* __restrict__ hpart,
                                               int* __restrict__ lseq) {
  __shared__ int lh[HBINS];
  #pragma unroll 1
  for (int ph = 0; ph < 8; ++ph) {
    const int* idx = (ph & 4) ? dst : src;
    int base = (ph & 3) * HBINS;
    for (int i = threadIdx.x; i < HBINS; i += 1024) lh[i] = 0;
    __syncthreads();
    if (ph & 4) {
      for (int e = blockIdx.x * 1024 + threadIdx.x; e < NE; e += HB * 1024) {
        int v = idx[e] - base;
        if ((unsigned)v < (unsigned)HBINS) lseq[e] = atomicAdd(&lh[v], 1);
      }
    } else {
      for (int e = blockIdx.x * 1024 + threadIdx.x; e < NE; e += HB * 1024) {
        int v = idx[e] - base;
        if ((unsigned)v < (unsigned)HBINS) atomicAdd(&lh[v], 1);
      }
    }
    __syncthreads();
    int* outp = hpart + ((size_t)ph * HB + blockIdx.x) * HBINS;
    for (int i = threadIdx.x; i < HBINS; i += 1024) outp[i] = lh[i];
    __syncthreads();
  }
}

// ---- merge partials -> degrees + norms; convert dst-phase partials IN PLACE
// to exclusive per-block offsets (for atomic-free CSR scatter). --------------
__global__ __launch_bounds__(256) void k_merge(int* __restrict__ hpart,
                                               int* __restrict__ ci,
                                               float* __restrict__ no,
                                               float* __restrict__ ni) {
  int i = blockIdx.x * 256 + threadIdx.x;
  if (i >= NN) return;
  int r = i / HBINS, bin = i - r * HBINS;
  const int* ps = hpart + ((size_t)(0 + r) * HB) * HBINS + bin;  // src phases
  int* pd = hpart + ((size_t)(4 + r) * HB) * HBINS + bin;        // dst phases
  int so = 0, si = 0;
  #pragma unroll 8
  for (int b = 0; b < HB; ++b) so += ps[(size_t)b * HBINS];
  #pragma unroll 8
  for (int b = 0; b < HB; ++b) {
    int* p = pd + (size_t)b * HBINS;
    int t = *p;
    *p = si;          // exclusive offset of this block within the bin
    si += t;
  }
  ci[i] = si;
  no[i] = rsqrtf((float)max(so, 1));
  ni[i] = rsqrtf((float)max(si, 1));
}

// ---------------- exclusive scan of in-degrees ----------------
__global__ __launch_bounds__(1024) void k_scanA(const int* __restrict__ deg,
                                                int* __restrict__ incl,
                                                int* __restrict__ bsum) {
  int tid = threadIdx.x;
  int gid = blockIdx.x * 1024 + tid;
  int v = (gid < NN) ? deg[gid] : 0;
  int lane = tid & 63;
  #pragma unroll
  for (int o = 1; o < 64; o <<= 1) {
    int n = __shfl_up(v, o);
    if (lane >= o) v += n;
  }
  __shared__ int ws[16];
  int wid = tid >> 6;
  if (lane == 63) ws[wid] = v;
  __syncthreads();
  if (tid < 16) {
    int s = ws[tid];
    #pragma unroll
    for (int o = 1; o < 16; o <<= 1) {
      int n = __shfl_up(s, o);
      if (tid >= o) s += n;
    }
    ws[tid] = s;
  }
  __syncthreads();
  if (wid > 0) v += ws[wid - 1];
  if (gid < NN) incl[gid] = v;
  if (tid == 1023) bsum[blockIdx.x] = v;
}

__global__ __launch_bounds__(64) void k_scanB(const int* __restrict__ bsum,
                                              int* __restrict__ boff, int nb) {
  int t = threadIdx.x;
  int v = (t < nb) ? bsum[t] : 0;
  int orig = v;
  #pragma unroll
  for (int o = 1; o < 64; o <<= 1) {
    int n = __shfl_up(v, o);
    if (t >= o) v += n;
  }
  if (t < nb) boff[t] = v - orig;  // exclusive
}

__global__ __launch_bounds__(256) void k_scanC(const int* __restrict__ incl,
                                               const int* __restrict__ deg,
                                               const int* __restrict__ boff,
                                               int* __restrict__ rp) {
  int i = blockIdx.x * 256 + threadIdx.x;
  if (i < NN) rp[i] = incl[i] - deg[i] + boff[i >> 10];
  if (i == 0) rp[NN] = NE;
}

// ---- CSR scatter, atomic-free: slot = rp[d] + blockofs(d, b(e)) + lseq[e] --
// b(e) is k_hist's deterministic edge->block mapping: (e>>10) & (HB-1).
__global__ __launch_bounds__(256) void k_scatter(const int* __restrict__ src,
                                                 const int* __restrict__ dst,
                                                 const int* __restrict__ lseq,
                                                 const int* __restrict__ hpart,
                                                 const int* __restrict__ rp,
                                                 int* __restrict__ colsrc) {
  int e = blockIdx.x * 256 + threadIdx.x;
  if (e >= NE) return;
  int d = dst[e];
  int r = d / HBINS, bin = d - r * HBINS;
  int b = (e >> 10) & (HB - 1);
  int ofs = hpart[((size_t)(4 + r) * HB + b) * HBINS + bin];
  colsrc[rp[d] + ofs + lseq[e]] = src[e];
}

// Edge loop with cascade tail (8/4/2/1): independent loads batched at every
// tail size — gathers are issue/latency-bound, serial singles were the cost.
#define GATHER_LOOP(LOADEXPR)                                        \
  for (int base = 0; base < cnt; base += 64) {                      \
    int e = beg + base + lane;                                      \
    int cv = (e < end) ? cs[e] : 0;                                 \
    int m = cnt - base; if (m > 64) m = 64;                         \
    int j = 0;                                                      \
    for (; j + 8 <= m; j += 8) {                                    \
      _Pragma("unroll")                                             \
      for (int u = 0; u < 8; ++u) {                                 \
        int s = __builtin_amdgcn_readlane(cv, j + u);               \
        LOADEXPR;                                                   \
      }                                                             \
    }                                                               \
    if (j + 4 <= m) {                                               \
      _Pragma("unroll")                                             \
      for (int u = 0; u < 4; ++u) {                                 \
        int s = __builtin_amdgcn_readlane(cv, j + u);               \
        LOADEXPR;                                                   \
      }                                                             \
      j += 4;                                                       \
    }                                                               \
    if (j + 2 <= m) {                                               \
      _Pragma("unroll")                                             \
      for (int u = 0; u < 2; ++u) {                                 \
        int s = __builtin_amdgcn_readlane(cv, j + u);               \
        LOADEXPR;                                                   \
      }                                                             \
      j += 2;                                                       \
    }                                                               \
    if (j < m) {                                                    \
      int s = __builtin_amdgcn_readlane(cv, j);                     \
      LOADEXPR;                                                     \
    }                                                               \
  }

// ---- APPNP iteration (fp8 source): r = 0.8*ni*sum(h8[s]) + 0.2*x0 ----------
// LAST=false: write fp8 scaled by no (next iteration's source).
// LAST=true:  write fp16 unscaled (h5).
template <bool LAST>
__global__ __launch_bounds__(256) void k_appnp8(const unsigned short* __restrict__ h8,
                                                const __half2* __restrict__ x0,
                                                const float* __restrict__ no,
                                                const float* __restrict__ ni,
                                                const int* __restrict__ rp,
                                                const int* __restrict__ cs,
                                                unsigned short* __restrict__ out8,
                                                __half2* __restrict__ out16) {
  int w = (blockIdx.x * 256 + threadIdx.x) >> 6;
  int lane = threadIdx.x & 63;
  if (w >= NN) return;
  const unsigned short* hl = h8 + lane;
  int beg = rp[w], end = rp[w + 1], cnt = end - beg;
  float ax = 0.f, ay = 0.f;
  GATHER_LOOP({
    float2 f = fp8_dec(hl[s * 64]);
    ax += f.x; ay += f.y;
  })
  float wi = 0.8f * ni[w];
  float2 xv = __half22float2(x0[w * 64 + lane]);
  float rx = wi * ax + 0.2f * xv.x;
  float ry = wi * ay + 0.2f * xv.y;
  if (LAST) {
    out16[w * 64 + lane] = __floats2half2_rn(rx, ry);
  } else {
    float sc = no[w];
    out8[w * 64 + lane] = fp8_enc(rx * sc, ry * sc);
  }
}

// packed-store helper: thread (node w, lane) holds features (2*lane, 2*lane+1)
__device__ inline void store_packed(_Float16* __restrict__ zp, int w, int lane,
                                    float v0, float v1) {
  int t = w >> 5, r = w & 31;
  int ks = lane >> 3, g = (lane >> 2) & 1, j = (lane & 3) * 2;
  size_t addr = (((size_t)t * 8 + ks) * 64 + g * 32 + r) * 8 + j;
  *reinterpret_cast<__half2*>(zp + addr) = __floats2half2_rn(v0, v1);
}

// ---- fused dual z-gather (fp16 x2): z1 = (1+e1)*h5[w] + agg(h5),
//                                     zx = (1+e2)*x0[w] + agg(x0) ------------
__global__ __launch_bounds__(256) void k_gz2(const __half2* __restrict__ h5,
                                             const __half2* __restrict__ x0,
                                             const float* __restrict__ eps1p,
                                             const float* __restrict__ eps2p,
                                             const int* __restrict__ rp,
                                             const int* __restrict__ cs,
                                             _Float16* __restrict__ z1out,
                                             _Float16* __restrict__ zxout) {
  int w = (blockIdx.x * 256 + threadIdx.x) >> 6;
  int lane = threadIdx.x & 63;
  if (w >= NN) return;
  const __half2* hl = h5 + lane;
  const __half2* xl = x0 + lane;
  int beg = rp[w], end = rp[w + 1], cnt = end - beg;
  float ax = 0.f, ay = 0.f, bx = 0.f, by = 0.f;
  GATHER_LOOP({
    float2 f = __half22float2(hl[s * 64]);
    float2 g2 = __half22float2(xl[s * 64]);
    ax += f.x; ay += f.y; bx += g2.x; by += g2.y;
  })
  float e1 = 1.0f + eps1p[0];
  float e2 = 1.0f + eps2p[0];
  float2 hv = __half22float2(h5[w * 64 + lane]);
  float2 xv = __half22float2(x0[w * 64 + lane]);
  store_packed(z1out, w, lane, e1 * hv.x + ax, e1 * hv.y + ay);
  store_packed(zxout, w, lane, e2 * xv.x + bx, e2 * xv.y + by);
}

// ---- gather + GIN affine, packed out: z = (1+eps)*h[w] + sum(h[s]) ---------
__global__ __launch_bounds__(256) void k_gather_z(const __half2* __restrict__ h,
                                                  const float* __restrict__ epsp,
                                                  const int* __restrict__ rp,
                                                  const int* __restrict__ cs,
                                                  _Float16* __restrict__ zout) {
  int w = (blockIdx.x * 256 + threadIdx.x) >> 6;
  int lane = threadIdx.x & 63;
  if (w >= NN) return;
  const __half2* hl = h + lane;
  int beg = rp[w], end = rp[w + 1], cnt = end - beg;
  float ax = 0.f, ay = 0.f;
  GATHER_LOOP({
    float2 f = __half22float2(hl[s * 64]);
    ax += f.x; ay += f.y;
  })
  float e1 = 1.0f + epsp[0];
  float2 hv = __half22float2(h[w * 64 + lane]);
  store_packed(zout, w, lane, e1 * hv.x + ax, e1 * hv.y + ay);
}

// ---- MFMA GEMM on packed operands: C = Z @ W + b -------------------------
template <int KTOT, bool MISH>
__global__ __launch_bounds__(64) void k_mgemm(const _Float16* __restrict__ z0,
                                              const _Float16* __restrict__ z1,
                                              const _Float16* __restrict__ wp,
                                              const float* __restrict__ bias,
                                              float* __restrict__ outf,
                                              __half2* __restrict__ outh) {
  int lane = threadIdx.x;
  int t = blockIdx.x;
  int row0 = t * 32;
  if (row0 >= NN) return;
  int r31 = lane & 31, g = lane >> 5;
  f32x16 acc[4];
  #pragma unroll
  for (int i = 0; i < 4; ++i) acc[i] = (f32x16)(0.0f);
  #pragma unroll 4
  for (int ks = 0; ks < KTOT / 16; ++ks) {
    const _Float16* zp = (KTOT == 256 && ks >= 8) ? z1 : z0;
    int kls = (KTOT == 256) ? (ks & 7) : ks;
    half8_t a = *reinterpret_cast<const half8_t*>(
        zp + (((size_t)t * 8 + kls) * 64 + lane) * 8);
    #pragma unroll
    for (int nb = 0; nb < 4; ++nb) {
      half8_t b = *reinterpret_cast<const half8_t*>(
          wp + (((size_t)ks * 4 + nb) * 64 + lane) * 8);
      acc[nb] = __builtin_amdgcn_mfma_f32_32x32x16_f16(a, b, acc[nb], 0, 0, 0);
    }
  }
  #pragma unroll
  for (int nb = 0; nb < 4; ++nb) {
    float bv = bias[nb * 32 + r31];
    #pragma unroll
    for (int r = 0; r < 16; ++r) {
      int rl = (r & 3) + 8 * (r >> 2) + 4 * g;
      int grow = row0 + rl;
      if (grow < NN) {
        float v = acc[nb][r] + bv;
        if (MISH) {
          // mish(v) = v*q/(q+2), q = E(E+2), E = e^v
          float E = __expf(v);
          float q = E * (E + 2.f);
          float mv = v * q / (q + 2.f);
          v = (v > 15.f) ? v : mv;
          outf[(size_t)grow * 128 + nb * 32 + r31] = v;
        } else {
          float u = __shfl_xor(v, 1);
          if (!(lane & 1)) {
            outh[((size_t)grow * 128 + nb * 32 + r31) >> 1] = __floats2half2_rn(v, u);
          }
        }
      }
    }
  }
}

extern "C" void kernel_launch(void* const* d_in, const int* in_sizes, int n_in,
                              void* d_out, int out_size, void* d_ws, size_t ws_size,
                              hipStream_t stream) {
  const float* x = (const float*)d_in[0];
  const int* src = (const int*)d_in[1];
  const int* dst = (const int*)d_in[2];
  const float* W1 = (const float*)d_in[3];
  const float* b1 = (const float*)d_in[4];
  const float* W2 = (const float*)d_in[5];
  const float* b2 = (const float*)d_in[6];
  const float* eps1 = (const float*)d_in[7];
  const float* eps2 = (const float*)d_in[8];
  float* out = (float*)d_out;

  char* ws = (char*)d_ws;
  size_t off = 0;
  auto alloc = [&](size_t bytes) -> void* {
    void* p = ws + off;
    off += (bytes + 255) & ~(size_t)255;
    return p;
  };
  const size_t NDP = (size_t)NT * 4096;  // halves per padded fp16 buffer
  __half2* x0h = (__half2*)alloc(NDP * 2);             // tanh(x), fp16
  unsigned short* x0n8 = (unsigned short*)alloc(NDP);  // fp8 tanh(x)*no
  unsigned short* hA8 = (unsigned short*)alloc(NDP);   // fp8 APPNP ping
  unsigned short* hB8 = (unsigned short*)alloc(NDP);   // fp8 APPNP pong
  __half2* h5 = (__half2*)alloc(NDP * 2);              // fp16 APPNP output
  __half2* zx = (__half2*)alloc(NDP * 2);              // packed (1+e2)*x0+agg(x0)
  __half2* z1p = (__half2*)alloc(NDP * 2);             // packed (1+e1)*h5+agg(h5)
  __half2* g1h = (__half2*)alloc(NDP * 2);             // GIN1 out, fp16
  __half2* zg = (__half2*)alloc(NDP * 2);              // packed (1+e2)*g1+agg(g1)
  _Float16* w1p = (_Float16*)alloc(128 * 128 * 2);
  _Float16* w2p = (_Float16*)alloc(256 * 128 * 2);
  int* ci = (int*)alloc(NN * 4);
  float* nrm_o = (float*)alloc(NN * 4);
  float* nrm_i = (float*)alloc(NN * 4);
  int* incl = (int*)alloc(NN * 4);
  int* bsum = (int*)alloc(64 * 4);
  int* boff = (int*)alloc(64 * 4);
  int* rp = (int*)alloc((NN + 1) * 4);
  int* lseq = (int*)alloc(NE * 4);
  int* colsrc = (int*)alloc(NE * 4);

  // histogram partials: 8 phases x HB x HBINS x 4B = 25.6 MB, aliased over
  // zx+z1p (contiguous 25.6 MB): consumed by k_scatter before either is written.
  int* hpart = (int*)zx;

  // degrees + per-edge sequence via LDS histogram (no global atomics)
  k_hist<<<HB, 1024, 0, stream>>>(src, dst, hpart, lseq);
  // merge -> ci, norms; dst partials -> exclusive per-block offsets (in place)
  k_merge<<<(NN + 255) / 256, 256, 0, stream>>>(hpart, ci, nrm_o, nrm_i);

  const int SB = (NN + 1023) / 1024;  // 49
  k_scanA<<<SB, 1024, 0, stream>>>(ci, incl, bsum);
  k_scanB<<<1, 64, 0, stream>>>(bsum, boff, SB);
  k_scanC<<<(NN + 255) / 256, 256, 0, stream>>>(incl, ci, boff, rp);
  const int EB = (NE + 255) / 256;
  k_scatter<<<EB, 256, 0, stream>>>(src, dst, lseq, hpart, rp, colsrc);

  k_tanh<<<(NN * 32 + 255) / 256, 256, 0, stream>>>(x, nrm_o, x0h,
                                                    (unsigned int*)x0n8);
  k_wt<<<192, 256, 0, stream>>>(W1, W2, w1p, w2p);

  const int GB = (NN * 64 + 255) / 256;  // one wave per node
  // APPNP iters 1..4 (fp8->fp8 scaled), iter 5 (fp8->fp16 unscaled)
  k_appnp8<false><<<GB, 256, 0, stream>>>(x0n8, x0h, nrm_o, nrm_i, rp, colsrc,
                                          hA8, nullptr);
  k_appnp8<false><<<GB, 256, 0, stream>>>(hA8, x0h, nrm_o, nrm_i, rp, colsrc,
                                          hB8, nullptr);
  k_appnp8<false><<<GB, 256, 0, stream>>>(hB8, x0h, nrm_o, nrm_i, rp, colsrc,
                                          hA8, nullptr);
  k_appnp8<false><<<GB, 256, 0, stream>>>(hA8, x0h, nrm_o, nrm_i, rp, colsrc,
                                          hB8, nullptr);
  k_appnp8<true><<<GB, 256, 0, stream>>>(hB8, x0h, nrm_o, nrm_i, rp, colsrc,
                                         nullptr, h5);

  // fused: z1 = (1+e1)*h5 + agg(h5) ; zx = (1+e2)*x0 + agg(x0)
  k_gz2<<<GB, 256, 0, stream>>>(h5, x0h, eps1, eps2, rp, colsrc,
                                (_Float16*)z1p, (_Float16*)zx);

  // GIN1: g1 = z1 @ W1 + b1 -> fp16 row-major
  k_mgemm<128, false><<<NT, 64, 0, stream>>>((const _Float16*)z1p, nullptr, w1p, b1,
                                             nullptr, g1h);
  // zg(packed) = (1+eps2)*g1 + agg(g1)   [fp16 source]
  k_gather_z<<<GB, 256, 0, stream>>>(g1h, eps2, rp, colsrc, (_Float16*)zg);
  // GIN2: out = mish([zg | zx] @ W2 + b2)
  k_mgemm<256, true><<<NT, 64, 0, stream>>>((const _Float16*)zg, (const _Float16*)zx,
                                            w2p, b2, out, nullptr);
}

// Round 13
// 288.248 us; speedup vs baseline: 2.3794x; 1.0402x over previous
//
#include <hip/hip_runtime.h>
#include <hip/hip_fp16.h>
#include <math.h>

#define NN 50000
#define NE 600000
#define NT ((NN + 31) / 32)   // 1563 row-tiles of 32

// histogram degree-count params
#define HB 64        // histogram blocks
#define HBINS 12500  // bins per phase (50KB LDS); 4 ranges x {src,dst} = 8 phases

typedef _Float16 half8_t __attribute__((ext_vector_type(8)));
typedef float f32x16 __attribute__((ext_vector_type(16)));
typedef float f32x2 __attribute__((ext_vector_type(2)));

union F2H { float2 f; __half2 h[2]; };

// fp8 e4m3 encode/decode via gfx950 HW cvt (self-consistent pair)
__device__ __forceinline__ float2 fp8_dec(unsigned short u) {
  f32x2 v = __builtin_amdgcn_cvt_pk_f32_fp8((unsigned int)u, false);
  float2 r; r.x = v.x; r.y = v.y; return r;
}
__device__ __forceinline__ unsigned short fp8_enc(float a, float b) {
  return (unsigned short)__builtin_amdgcn_cvt_pk_fp8_f32(a, b, 0u, false);
}

// Packed fragment layout for MFMA (32x32x16_f16):
//   element (row r in tile t, feature k): ks=k>>4, g=(k&15)>>3, j=k&7
//   halves index = ((t*8 + ks)*64 + g*32 + r)*8 + j   (per 128-k buffer)

// -- tanh -> fp16 (self/residual) + fp8*no (APPNP src) + fp8 plain (zx-agg) --
__global__ __launch_bounds__(256) void k_tanh(const float* __restrict__ x,
                                              const float* __restrict__ no,
                                              __half2* __restrict__ x0h,
                                              unsigned int* __restrict__ x0n8,
                                              unsigned int* __restrict__ x0p8) {
  int i = blockIdx.x * 256 + threadIdx.x;
  if (i >= NN * 32) return;
  float4 v = reinterpret_cast<const float4*>(x)[i];
  float t[4];
  float vv[4] = {v.x, v.y, v.z, v.w};
  #pragma unroll
  for (int j = 0; j < 4; ++j) {
    float xc = fminf(fmaxf(vv[j], -9.f), 9.f);
    float E = __expf(2.f * xc);
    t[j] = (E - 1.f) / (E + 1.f);
  }
  float s = no[i >> 5];  // 32 float4 per node row
  F2H a;
  a.h[0] = __floats2half2_rn(t[0], t[1]);
  a.h[1] = __floats2half2_rn(t[2], t[3]);
  reinterpret_cast<float2*>(x0h)[i] = a.f;
  unsigned int p = __builtin_amdgcn_cvt_pk_fp8_f32(t[0] * s, t[1] * s, 0u, false);
  p = __builtin_amdgcn_cvt_pk_fp8_f32(t[2] * s, t[3] * s, p, true);
  x0n8[i] = p;
  unsigned int q = __builtin_amdgcn_cvt_pk_fp8_f32(t[0], t[1], 0u, false);
  q = __builtin_amdgcn_cvt_pk_fp8_f32(t[2], t[3], q, true);
  x0p8[i] = q;
}

// ------------- W transpose -> fragment-packed fp16 (runs once, tiny) --------
__global__ __launch_bounds__(256) void k_wt(const float* __restrict__ W1,
                                            const float* __restrict__ W2,
                                            _Float16* __restrict__ w1p,
                                            _Float16* __restrict__ w2p) {
  int i = blockIdx.x * 256 + threadIdx.x;
  if (i < 128 * 128) {
    int k = i >> 7, n = i & 127;
    int nb = n >> 5, r = n & 31, ks = k >> 4, g = (k & 15) >> 3, j = k & 7;
    w1p[(((ks << 2) + nb) * 64 + (g << 5) + r) * 8 + j] = (_Float16)W1[i];
  } else {
    int q = i - 128 * 128;
    if (q < 256 * 128) {
      int k = q >> 7, n = q & 127;
      int nb = n >> 5, r = n & 31, ks = k >> 4, g = (k & 15) >> 3, j = k & 7;
      w2p[(((ks << 2) + nb) * 64 + (g << 5) + r) * 8 + j] = (_Float16)W2[q];
    }
  }
}

// ---- degree count via LDS-privatized histogram. dst phases additionally
// record each edge's within-(block,bin) sequence via returning LDS atomic. ----
__global__ __launch_bounds__(1024) void k_hist(const int* __restrict__ src,
                                               const int* __restrict__ dst,
                                               int* __restrict__ hpart,
                                               int* __restrict__ lseq) {
  __shared__ int lh[HBINS];
  #pragma unroll 1
  for (int ph = 0; ph < 8; ++ph) {
    const int* idx = (ph & 4) ? dst : src;
    int base = (ph & 3) * HBINS;
    for (int i = threadIdx.x; i < HBINS; i += 1024) lh[i] = 0;
    __syncthreads();
    if (ph & 4) {
      for (int e = blockIdx.x * 1024 + threadIdx.x; e < NE; e += HB * 1024) {
        int v = idx[e] - base;
        if ((unsigned)v < (unsigned)HBINS) lseq[e] = atomicAdd(&lh[v], 1);
      }
    } else {
      for (int e = blockIdx.x * 1024 + threadIdx.x; e < NE; e += HB * 1024) {
        int v = idx[e] - base;
        if ((unsigned)v < (unsigned)HBINS) atomicAdd(&lh[v], 1);
      }
    }
    __syncthreads();
    int* outp = hpart + ((size_t)ph * HB + blockIdx.x) * HBINS;
    for (int i = threadIdx.x; i < HBINS; i += 1024) outp[i] = lh[i];
    __syncthreads();
  }
}

// ---- merge partials -> degrees + norms; convert dst-phase partials IN PLACE
// to exclusive per-block offsets (for atomic-free CSR scatter). --------------
__global__ __launch_bounds__(256) void k_merge(int* __restrict__ hpart,
                                               int* __restrict__ ci,
                                               float* __restrict__ no,
                                               float* __restrict__ ni) {
  int i = blockIdx.x * 256 + threadIdx.x;
  if (i >= NN) return;
  int r = i / HBINS, bin = i - r * HBINS;
  const int* ps = hpart + ((size_t)(0 + r) * HB) * HBINS + bin;  // src phases
  int* pd = hpart + ((size_t)(4 + r) * HB) * HBINS + bin;        // dst phases
  int so = 0, si = 0;
  #pragma unroll 8
  for (int b = 0; b < HB; ++b) so += ps[(size_t)b * HBINS];
  #pragma unroll 8
  for (int b = 0; b < HB; ++b) {
    int* p = pd + (size_t)b * HBINS;
    int t = *p;
    *p = si;          // exclusive offset of this block within the bin
    si += t;
  }
  ci[i] = si;
  no[i] = rsqrtf((float)max(so, 1));
  ni[i] = rsqrtf((float)max(si, 1));
}

// ---------------- exclusive scan of in-degrees ----------------
__global__ __launch_bounds__(1024) void k_scanA(const int* __restrict__ deg,
                                                int* __restrict__ incl,
                                                int* __restrict__ bsum) {
  int tid = threadIdx.x;
  int gid = blockIdx.x * 1024 + tid;
  int v = (gid < NN) ? deg[gid] : 0;
  int lane = tid & 63;
  #pragma unroll
  for (int o = 1; o < 64; o <<= 1) {
    int n = __shfl_up(v, o);
    if (lane >= o) v += n;
  }
  __shared__ int ws[16];
  int wid = tid >> 6;
  if (lane == 63) ws[wid] = v;
  __syncthreads();
  if (tid < 16) {
    int s = ws[tid];
    #pragma unroll
    for (int o = 1; o < 16; o <<= 1) {
      int n = __shfl_up(s, o);
      if (tid >= o) s += n;
    }
    ws[tid] = s;
  }
  __syncthreads();
  if (wid > 0) v += ws[wid - 1];
  if (gid < NN) incl[gid] = v;
  if (tid == 1023) bsum[blockIdx.x] = v;
}

__global__ __launch_bounds__(64) void k_scanB(const int* __restrict__ bsum,
                                              int* __restrict__ boff, int nb) {
  int t = threadIdx.x;
  int v = (t < nb) ? bsum[t] : 0;
  int orig = v;
  #pragma unroll
  for (int o = 1; o < 64; o <<= 1) {
    int n = __shfl_up(v, o);
    if (t >= o) v += n;
  }
  if (t < nb) boff[t] = v - orig;  // exclusive
}

__global__ __launch_bounds__(256) void k_scanC(const int* __restrict__ incl,
                                               const int* __restrict__ deg,
                                               const int* __restrict__ boff,
                                               int* __restrict__ rp) {
  int i = blockIdx.x * 256 + threadIdx.x;
  if (i < NN) rp[i] = incl[i] - deg[i] + boff[i >> 10];
  if (i == 0) rp[NN] = NE;
}

// ---- CSR scatter, atomic-free: slot = rp[d] + blockofs(d, b(e)) + lseq[e] --
// b(e) is k_hist's deterministic edge->block mapping: (e>>10) & (HB-1).
__global__ __launch_bounds__(256) void k_scatter(const int* __restrict__ src,
                                                 const int* __restrict__ dst,
                                                 const int* __restrict__ lseq,
                                                 const int* __restrict__ hpart,
                                                 const int* __restrict__ rp,
                                                 int* __restrict__ colsrc) {
  int e = blockIdx.x * 256 + threadIdx.x;
  if (e >= NE) return;
  int d = dst[e];
  int r = d / HBINS, bin = d - r * HBINS;
  int b = (e >> 10) & (HB - 1);
  int ofs = hpart[((size_t)(4 + r) * HB + b) * HBINS + bin];
  colsrc[rp[d] + ofs + lseq[e]] = src[e];
}

// Edge loop with cascade tail (8/4/2/1): independent loads batched at every
// tail size — gathers are issue/latency-bound, serial singles were the cost.
#define GATHER_LOOP(LOADEXPR)                                        \
  for (int base = 0; base < cnt; base += 64) {                      \
    int e = beg + base + lane;                                      \
    int cv = (e < end) ? cs[e] : 0;                                 \
    int m = cnt - base; if (m > 64) m = 64;                         \
    int j = 0;                                                      \
    for (; j + 8 <= m; j += 8) {                                    \
      _Pragma("unroll")                                             \
      for (int u = 0; u < 8; ++u) {                                 \
        int s = __builtin_amdgcn_readlane(cv, j + u);               \
        LOADEXPR;                                                   \
      }                                                             \
    }                                                               \
    if (j + 4 <= m) {                                               \
      _Pragma("unroll")                                             \
      for (int u = 0; u < 4; ++u) {                                 \
        int s = __builtin_amdgcn_readlane(cv, j + u);               \
        LOADEXPR;                                                   \
      }                                                             \
      j += 4;                                                       \
    }                                                               \
    if (j + 2 <= m) {                                               \
      _Pragma("unroll")                                             \
      for (int u = 0; u < 2; ++u) {                                 \
        int s = __builtin_amdgcn_readlane(cv, j + u);               \
        LOADEXPR;                                                   \
      }                                                             \
      j += 2;                                                       \
    }                                                               \
    if (j < m) {                                                    \
      int s = __builtin_amdgcn_readlane(cv, j);                     \
      LOADEXPR;                                                     \
    }                                                               \
  }

// ---- APPNP iteration (fp8 source): r = 0.8*ni*sum(h8[s]) + 0.2*x0 ----------
// LAST=false: write fp8 scaled by no (next iteration's source).
// LAST=true:  write fp16 unscaled (h5).
template <bool LAST>
__global__ __launch_bounds__(256) void k_appnp8(const unsigned short* __restrict__ h8,
                                                const __half2* __restrict__ x0,
                                                const float* __restrict__ no,
                                                const float* __restrict__ ni,
                                                const int* __restrict__ rp,
                                                const int* __restrict__ cs,
                                                unsigned short* __restrict__ out8,
                                                __half2* __restrict__ out16) {
  int w = (blockIdx.x * 256 + threadIdx.x) >> 6;
  int lane = threadIdx.x & 63;
  if (w >= NN) return;
  const unsigned short* hl = h8 + lane;
  int beg = rp[w], end = rp[w + 1], cnt = end - beg;
  float ax = 0.f, ay = 0.f;
  GATHER_LOOP({
    float2 f = fp8_dec(hl[s * 64]);
    ax += f.x; ay += f.y;
  })
  float wi = 0.8f * ni[w];
  float2 xv = __half22float2(x0[w * 64 + lane]);
  float rx = wi * ax + 0.2f * xv.x;
  float ry = wi * ay + 0.2f * xv.y;
  if (LAST) {
    out16[w * 64 + lane] = __floats2half2_rn(rx, ry);
  } else {
    float sc = no[w];
    out8[w * 64 + lane] = fp8_enc(rx * sc, ry * sc);
  }
}

// packed-store helper: thread (node w, lane) holds features (2*lane, 2*lane+1)
__device__ inline void store_packed(_Float16* __restrict__ zp, int w, int lane,
                                    float v0, float v1) {
  int t = w >> 5, r = w & 31;
  int ks = lane >> 3, g = (lane >> 2) & 1, j = (lane & 3) * 2;
  size_t addr = (((size_t)t * 8 + ks) * 64 + g * 32 + r) * 8 + j;
  *reinterpret_cast<__half2*>(zp + addr) = __floats2half2_rn(v0, v1);
}

// ---- APPNP pass 1 fused with zx-agg: DUAL fp8 gather (4 lines/edge) --------
// hout8 = fp8( no*(0.8*ni*sum(x0n8[s]) + 0.2*x0[w]) )
// zxout(packed fp16) = (1+eps2)*x0[w] + sum(x0p8[s])
// zx-agg in fp8 is numerically safe (one GEMM downstream, no aggregation
// amplification — r8's failure was the z1 path, amplified by agg(g1)).
__global__ __launch_bounds__(256) void k_appnp_first8(const unsigned short* __restrict__ xn8,
                                                      const unsigned short* __restrict__ xp8,
                                                      const __half2* __restrict__ xp,
                                                      const float* __restrict__ epsp,
                                                      const float* __restrict__ no,
                                                      const float* __restrict__ ni,
                                                      const int* __restrict__ rp,
                                                      const int* __restrict__ cs,
                                                      unsigned short* __restrict__ hout8,
                                                      _Float16* __restrict__ zxout) {
  int w = (blockIdx.x * 256 + threadIdx.x) >> 6;
  int lane = threadIdx.x & 63;
  if (w >= NN) return;
  const unsigned short* xnl = xn8 + lane;
  const unsigned short* xpl = xp8 + lane;
  int beg = rp[w], end = rp[w + 1], cnt = end - beg;
  float ax = 0.f, ay = 0.f, bx = 0.f, by = 0.f;
  GATHER_LOOP({
    float2 f = fp8_dec(xnl[s * 64]);
    float2 g2 = fp8_dec(xpl[s * 64]);
    ax += f.x; ay += f.y; bx += g2.x; by += g2.y;
  })
  float2 xv = __half22float2(xp[w * 64 + lane]);
  float wi = 0.8f * ni[w];
  float sc = no[w];
  hout8[w * 64 + lane] = fp8_enc(sc * (wi * ax + 0.2f * xv.x),
                                 sc * (wi * ay + 0.2f * xv.y));
  float e2 = 1.0f + epsp[0];
  store_packed(zxout, w, lane, e2 * xv.x + bx, e2 * xv.y + by);
}

// ---- gather + GIN affine, packed out: z = (1+eps)*h[w] + sum(h[s]) ---------
__global__ __launch_bounds__(256) void k_gather_z(const __half2* __restrict__ h,
                                                  const float* __restrict__ epsp,
                                                  const int* __restrict__ rp,
                                                  const int* __restrict__ cs,
                                                  _Float16* __restrict__ zout) {
  int w = (blockIdx.x * 256 + threadIdx.x) >> 6;
  int lane = threadIdx.x & 63;
  if (w >= NN) return;
  const __half2* hl = h + lane;
  int beg = rp[w], end = rp[w + 1], cnt = end - beg;
  float ax = 0.f, ay = 0.f;
  GATHER_LOOP({
    float2 f = __half22float2(hl[s * 64]);
    ax += f.x; ay += f.y;
  })
  float e1 = 1.0f + epsp[0];
  float2 hv = __half22float2(h[w * 64 + lane]);
  store_packed(zout, w, lane, e1 * hv.x + ax, e1 * hv.y + ay);
}

// ---- MFMA GEMM on packed operands: C = Z @ W + b -------------------------
template <int KTOT, bool MISH>
__global__ __launch_bounds__(64) void k_mgemm(const _Float16* __restrict__ z0,
                                              const _Float16* __restrict__ z1,
                                              const _Float16* __restrict__ wp,
                                              const float* __restrict__ bias,
                                              float* __restrict__ outf,
                                              __half2* __restrict__ outh) {
  int lane = threadIdx.x;
  int t = blockIdx.x;
  int row0 = t * 32;
  if (row0 >= NN) return;
  int r31 = lane & 31, g = lane >> 5;
  f32x16 acc[4];
  #pragma unroll
  for (int i = 0; i < 4; ++i) acc[i] = (f32x16)(0.0f);
  #pragma unroll 4
  for (int ks = 0; ks < KTOT / 16; ++ks) {
    const _Float16* zp = (KTOT == 256 && ks >= 8) ? z1 : z0;
    int kls = (KTOT == 256) ? (ks & 7) : ks;
    half8_t a = *reinterpret_cast<const half8_t*>(
        zp + (((size_t)t * 8 + kls) * 64 + lane) * 8);
    #pragma unroll
    for (int nb = 0; nb < 4; ++nb) {
      half8_t b = *reinterpret_cast<const half8_t*>(
          wp + (((size_t)ks * 4 + nb) * 64 + lane) * 8);
      acc[nb] = __builtin_amdgcn_mfma_f32_32x32x16_f16(a, b, acc[nb], 0, 0, 0);
    }
  }
  #pragma unroll
  for (int nb = 0; nb < 4; ++nb) {
    float bv = bias[nb * 32 + r31];
    #pragma unroll
    for (int r = 0; r < 16; ++r) {
      int rl = (r & 3) + 8 * (r >> 2) + 4 * g;
      int grow = row0 + rl;
      if (grow < NN) {
        float v = acc[nb][r] + bv;
        if (MISH) {
          // mish(v) = v*q/(q+2), q = E(E+2), E = e^v
          float E = __expf(v);
          float q = E * (E + 2.f);
          float mv = v * q / (q + 2.f);
          v = (v > 15.f) ? v : mv;
          outf[(size_t)grow * 128 + nb * 32 + r31] = v;
        } else {
          float u = __shfl_xor(v, 1);
          if (!(lane & 1)) {
            outh[((size_t)grow * 128 + nb * 32 + r31) >> 1] = __floats2half2_rn(v, u);
          }
        }
      }
    }
  }
}

extern "C" void kernel_launch(void* const* d_in, const int* in_sizes, int n_in,
                              void* d_out, int out_size, void* d_ws, size_t ws_size,
                              hipStream_t stream) {
  const float* x = (const float*)d_in[0];
  const int* src = (const int*)d_in[1];
  const int* dst = (const int*)d_in[2];
  const float* W1 = (const float*)d_in[3];
  const float* b1 = (const float*)d_in[4];
  const float* W2 = (const float*)d_in[5];
  const float* b2 = (const float*)d_in[6];
  const float* eps1 = (const float*)d_in[7];
  const float* eps2 = (const float*)d_in[8];
  float* out = (float*)d_out;

  char* ws = (char*)d_ws;
  size_t off = 0;
  auto alloc = [&](size_t bytes) -> void* {
    void* p = ws + off;
    off += (bytes + 255) & ~(size_t)255;
    return p;
  };
  const size_t NDP = (size_t)NT * 4096;  // halves per padded fp16 buffer
  __half2* x0h = (__half2*)alloc(NDP * 2);             // tanh(x), fp16
  unsigned short* x0n8 = (unsigned short*)alloc(NDP);  // fp8 tanh(x)*no
  unsigned short* x0p8 = (unsigned short*)alloc(NDP);  // fp8 tanh(x) plain
  unsigned short* hA8 = (unsigned short*)alloc(NDP);   // fp8 APPNP ping
  unsigned short* hB8 = (unsigned short*)alloc(NDP);   // fp8 APPNP pong
  __half2* h5 = (__half2*)alloc(NDP * 2);              // fp16 APPNP output
  __half2* zx = (__half2*)alloc(NDP * 2);              // packed (1+e2)*x0+agg(x0)
  __half2* z1p = (__half2*)alloc(NDP * 2);             // packed (1+e1)*h5+agg(h5)
  __half2* g1h = (__half2*)alloc(NDP * 2);             // GIN1 out, fp16
  __half2* zg = (__half2*)alloc(NDP * 2);              // packed (1+e2)*g1+agg(g1)
  _Float16* w1p = (_Float16*)alloc(128 * 128 * 2);
  _Float16* w2p = (_Float16*)alloc(256 * 128 * 2);
  int* ci = (int*)alloc(NN * 4);
  float* nrm_o = (float*)alloc(NN * 4);
  float* nrm_i = (float*)alloc(NN * 4);
  int* incl = (int*)alloc(NN * 4);
  int* bsum = (int*)alloc(64 * 4);
  int* boff = (int*)alloc(64 * 4);
  int* rp = (int*)alloc((NN + 1) * 4);
  int* lseq = (int*)alloc(NE * 4);
  int* colsrc = (int*)alloc(NE * 4);

  // histogram partials: 8 phases x HB x HBINS x 4B = 25.6 MB, aliased over
  // zx+z1p (contiguous 25.6 MB): consumed by k_scatter before either is written.
  int* hpart = (int*)zx;

  // degrees + per-edge sequence via LDS histogram (no global atomics)
  k_hist<<<HB, 1024, 0, stream>>>(src, dst, hpart, lseq);
  // merge -> ci, norms; dst partials -> exclusive per-block offsets (in place)
  k_merge<<<(NN + 255) / 256, 256, 0, stream>>>(hpart, ci, nrm_o, nrm_i);

  const int SB = (NN + 1023) / 1024;  // 49
  k_scanA<<<SB, 1024, 0, stream>>>(ci, incl, bsum);
  k_scanB<<<1, 64, 0, stream>>>(bsum, boff, SB);
  k_scanC<<<(NN + 255) / 256, 256, 0, stream>>>(incl, ci, boff, rp);
  const int EB = (NE + 255) / 256;
  k_scatter<<<EB, 256, 0, stream>>>(src, dst, lseq, hpart, rp, colsrc);

  k_tanh<<<(NN * 32 + 255) / 256, 256, 0, stream>>>(x, nrm_o, x0h,
                                                    (unsigned int*)x0n8,
                                                    (unsigned int*)x0p8);
  k_wt<<<192, 256, 0, stream>>>(W1, W2, w1p, w2p);

  const int GB = (NN * 64 + 255) / 256;  // one wave per node
  // APPNP pass 1 fused with zx-agg (dual fp8 gather) -> hA8, zx(packed)
  k_appnp_first8<<<GB, 256, 0, stream>>>(x0n8, x0p8, x0h, eps2, nrm_o, nrm_i,
                                         rp, colsrc, hA8, (_Float16*)zx);
  // APPNP passes 2..4 (fp8->fp8 scaled), pass 5 (fp8->fp16 unscaled)
  k_appnp8<false><<<GB, 256, 0, stream>>>(hA8, x0h, nrm_o, nrm_i, rp, colsrc,
                                          hB8, nullptr);
  k_appnp8<false><<<GB, 256, 0, stream>>>(hB8, x0h, nrm_o, nrm_i, rp, colsrc,
                                          hA8, nullptr);
  k_appnp8<false><<<GB, 256, 0, stream>>>(hA8, x0h, nrm_o, nrm_i, rp, colsrc,
                                          hB8, nullptr);
  k_appnp8<true><<<GB, 256, 0, stream>>>(hB8, x0h, nrm_o, nrm_i, rp, colsrc,
                                         nullptr, h5);

  // z1(packed) = (1+eps1)*h5 + agg(h5)   [fp16 source — accuracy-critical]
  k_gather_z<<<GB, 256, 0, stream>>>(h5, eps1, rp, colsrc, (_Float16*)z1p);

  // GIN1: g1 = z1 @ W1 + b1 -> fp16 row-major
  k_mgemm<128, false><<<NT, 64, 0, stream>>>((const _Float16*)z1p, nullptr, w1p, b1,
                                             nullptr, g1h);
  // zg(packed) = (1+eps2)*g1 + agg(g1)   [fp16 source — accuracy-critical]
  k_gather_z<<<GB, 256, 0, stream>>>(g1h, eps2, rp, colsrc, (_Float16*)zg);
  // GIN2: out = mish([zg | zx] @ W2 + b2)
  k_mgemm<256, true><<<NT, 64, 0, stream>>>((const _Float16*)zg, (const _Float16*)zx,
                                            w2p, b2, out, nullptr);
}

// Round 14
// 274.965 us; speedup vs baseline: 2.4943x; 1.0483x over previous
//
#include <hip/hip_runtime.h>
#include <hip/hip_fp16.h>
#include <math.h>

#define NN 50000
#define NE 600000
#define NT ((NN + 31) / 32)   // 1563 row-tiles of 32

#define HB 64          // histogram blocks
#define NBIN2 25000    // packed bins: node i and i+25000 share one u32 (2x u16)

typedef _Float16 half8_t __attribute__((ext_vector_type(8)));
typedef float f32x16 __attribute__((ext_vector_type(16)));
typedef float f32x2 __attribute__((ext_vector_type(2)));

union F2H { float2 f; __half2 h[2]; };

// fp8 e4m3 encode/decode via gfx950 HW cvt (self-consistent pair)
__device__ __forceinline__ float2 fp8_dec(unsigned short u) {
  f32x2 v = __builtin_amdgcn_cvt_pk_f32_fp8((unsigned int)u, false);
  float2 r; r.x = v.x; r.y = v.y; return r;
}
__device__ __forceinline__ unsigned short fp8_enc(float a, float b) {
  return (unsigned short)__builtin_amdgcn_cvt_pk_fp8_f32(a, b, 0u, false);
}

// Packed fragment layout for MFMA (32x32x16_f16):
//   element (row r in tile t, feature k): ks=k>>4, g=(k&15)>>3, j=k&7
//   halves index = ((t*8 + ks)*64 + g*32 + r)*8 + j   (per 128-k buffer)

// -- tanh -> fp16 (self/residual) + fp8*no (APPNP src) + fp8 plain (zx-agg) --
__global__ __launch_bounds__(256) void k_tanh(const float* __restrict__ x,
                                              const float* __restrict__ no,
                                              __half2* __restrict__ x0h,
                                              unsigned int* __restrict__ x0n8,
                                              unsigned int* __restrict__ x0p8) {
  int i = blockIdx.x * 256 + threadIdx.x;
  if (i >= NN * 32) return;
  float4 v = reinterpret_cast<const float4*>(x)[i];
  float t[4];
  float vv[4] = {v.x, v.y, v.z, v.w};
  #pragma unroll
  for (int j = 0; j < 4; ++j) {
    float xc = fminf(fmaxf(vv[j], -9.f), 9.f);
    float E = __expf(2.f * xc);
    t[j] = (E - 1.f) / (E + 1.f);
  }
  float s = no[i >> 5];  // 32 float4 per node row
  F2H a;
  a.h[0] = __floats2half2_rn(t[0], t[1]);
  a.h[1] = __floats2half2_rn(t[2], t[3]);
  reinterpret_cast<float2*>(x0h)[i] = a.f;
  unsigned int p = __builtin_amdgcn_cvt_pk_fp8_f32(t[0] * s, t[1] * s, 0u, false);
  p = __builtin_amdgcn_cvt_pk_fp8_f32(t[2] * s, t[3] * s, p, true);
  x0n8[i] = p;
  unsigned int q = __builtin_amdgcn_cvt_pk_fp8_f32(t[0], t[1], 0u, false);
  q = __builtin_amdgcn_cvt_pk_fp8_f32(t[2], t[3], q, true);
  x0p8[i] = q;
}

// ------------- W transpose -> fragment-packed fp16 (runs once, tiny) --------
__global__ __launch_bounds__(256) void k_wt(const float* __restrict__ W1,
                                            const float* __restrict__ W2,
                                            _Float16* __restrict__ w1p,
                                            _Float16* __restrict__ w2p) {
  int i = blockIdx.x * 256 + threadIdx.x;
  if (i < 128 * 128) {
    int k = i >> 7, n = i & 127;
    int nb = n >> 5, r = n & 31, ks = k >> 4, g = (k & 15) >> 3, j = k & 7;
    w1p[(((ks << 2) + nb) * 64 + (g << 5) + r) * 8 + j] = (_Float16)W1[i];
  } else {
    int q = i - 128 * 128;
    if (q < 256 * 128) {
      int k = q >> 7, n = q & 127;
      int nb = n >> 5, r = n & 31, ks = k >> 4, g = (k & 15) >> 3, j = k & 7;
      w2p[(((ks << 2) + nb) * 64 + (g << 5) + r) * 8 + j] = (_Float16)W2[q];
    }
  }
}

// ---- 2-phase LDS histogram: two u16 counters packed per u32 word.
// Node v -> word (v % 25000), half (v / 25000). Max per-block count << 2^16.
// Phase 0 = src (out-degree), phase 1 = dst (in-degree, records lseq). -------
__global__ __launch_bounds__(1024) void k_hist2(const int* __restrict__ src,
                                                const int* __restrict__ dst,
                                                unsigned int* __restrict__ hpart,
                                                int* __restrict__ lseq) {
  __shared__ unsigned int lh[NBIN2];
  #pragma unroll 1
  for (int ph = 0; ph < 2; ++ph) {
    const int* idx = ph ? dst : src;
    for (int i = threadIdx.x; i < NBIN2; i += 1024) lh[i] = 0;
    __syncthreads();
    if (ph) {
      for (int e = blockIdx.x * 1024 + threadIdx.x; e < NE; e += HB * 1024) {
        int v = idx[e];
        int hi = (v >= NBIN2) ? 1 : 0;
        int bin = v - hi * NBIN2;
        unsigned int old = atomicAdd(&lh[bin], hi ? 65536u : 1u);
        lseq[e] = (int)((old >> (hi * 16)) & 0xffffu);
      }
    } else {
      for (int e = blockIdx.x * 1024 + threadIdx.x; e < NE; e += HB * 1024) {
        int v = idx[e];
        int hi = (v >= NBIN2) ? 1 : 0;
        atomicAdd(&lh[v - hi * NBIN2], hi ? 65536u : 1u);
      }
    }
    __syncthreads();
    unsigned int* outp = hpart + ((size_t)ph * HB + blockIdx.x) * NBIN2;
    for (int i = threadIdx.x; i < NBIN2; i += 1024) outp[i] = lh[i];
    __syncthreads();
  }
}

// ---- merge packed partials -> degrees + norms; dst partials -> exclusive
// per-block offsets IN PLACE (both packed halves handled by one thread). ----
__global__ __launch_bounds__(256) void k_merge2(unsigned int* __restrict__ hpart,
                                                int* __restrict__ ci,
                                                float* __restrict__ no,
                                                float* __restrict__ ni) {
  int bin = blockIdx.x * 256 + threadIdx.x;
  if (bin >= NBIN2) return;
  const unsigned int* ps = hpart + bin;                    // src phase
  unsigned int* pd = hpart + (size_t)HB * NBIN2 + bin;     // dst phase
  unsigned int so0 = 0, so1 = 0, si0 = 0, si1 = 0;
  #pragma unroll 8
  for (int b = 0; b < HB; ++b) {
    unsigned int v = ps[(size_t)b * NBIN2];
    so0 += v & 0xffffu; so1 += v >> 16;
  }
  #pragma unroll 8
  for (int b = 0; b < HB; ++b) {
    unsigned int* p = pd + (size_t)b * NBIN2;
    unsigned int v = *p;
    *p = si0 | (si1 << 16);       // exclusive offsets, packed
    si0 += v & 0xffffu; si1 += v >> 16;
  }
  ci[bin] = (int)si0;
  ci[bin + NBIN2] = (int)si1;
  no[bin] = rsqrtf((float)max((int)so0, 1));
  no[bin + NBIN2] = rsqrtf((float)max((int)so1, 1));
  ni[bin] = rsqrtf((float)max((int)si0, 1));
  ni[bin + NBIN2] = rsqrtf((float)max((int)si1, 1));
}

// ---------------- exclusive scan of in-degrees ----------------
__global__ __launch_bounds__(1024) void k_scanA(const int* __restrict__ deg,
                                                int* __restrict__ incl,
                                                int* __restrict__ bsum) {
  int tid = threadIdx.x;
  int gid = blockIdx.x * 1024 + tid;
  int v = (gid < NN) ? deg[gid] : 0;
  int lane = tid & 63;
  #pragma unroll
  for (int o = 1; o < 64; o <<= 1) {
    int n = __shfl_up(v, o);
    if (lane >= o) v += n;
  }
  __shared__ int ws[16];
  int wid = tid >> 6;
  if (lane == 63) ws[wid] = v;
  __syncthreads();
  if (tid < 16) {
    int s = ws[tid];
    #pragma unroll
    for (int o = 1; o < 16; o <<= 1) {
      int n = __shfl_up(s, o);
      if (tid >= o) s += n;
    }
    ws[tid] = s;
  }
  __syncthreads();
  if (wid > 0) v += ws[wid - 1];
  if (gid < NN) incl[gid] = v;
  if (tid == 1023) bsum[blockIdx.x] = v;
}

__global__ __launch_bounds__(64) void k_scanB(const int* __restrict__ bsum,
                                              int* __restrict__ boff, int nb) {
  int t = threadIdx.x;
  int v = (t < nb) ? bsum[t] : 0;
  int orig = v;
  #pragma unroll
  for (int o = 1; o < 64; o <<= 1) {
    int n = __shfl_up(v, o);
    if (t >= o) v += n;
  }
  if (t < nb) boff[t] = v - orig;  // exclusive
}

__global__ __launch_bounds__(256) void k_scanC(const int* __restrict__ incl,
                                               const int* __restrict__ deg,
                                               const int* __restrict__ boff,
                                               int* __restrict__ rp) {
  int i = blockIdx.x * 256 + threadIdx.x;
  if (i < NN) rp[i] = incl[i] - deg[i] + boff[i >> 10];
  if (i == 0) rp[NN] = NE;
}

// ---- CSR scatter, atomic-free: slot = rp[d] + blockofs(d, b(e)) + lseq[e] --
// b(e) is k_hist2's deterministic edge->block mapping: (e>>10) & (HB-1).
__global__ __launch_bounds__(256) void k_scatter(const int* __restrict__ src,
                                                 const int* __restrict__ dst,
                                                 const int* __restrict__ lseq,
                                                 const unsigned int* __restrict__ hpart,
                                                 const int* __restrict__ rp,
                                                 int* __restrict__ colsrc) {
  int e = blockIdx.x * 256 + threadIdx.x;
  if (e >= NE) return;
  int d = dst[e];
  int hi = (d >= NBIN2) ? 1 : 0;
  int bin = d - hi * NBIN2;
  int b = (e >> 10) & (HB - 1);
  unsigned int w = hpart[((size_t)HB + b) * NBIN2 + bin];
  int ofs = (int)((w >> (hi * 16)) & 0xffffu);
  colsrc[rp[d] + ofs + lseq[e]] = src[e];
}

// Edge loop with cascade tail (8/4/2/1): independent loads batched at every
// tail size — gathers are issue/latency-bound, serial singles were the cost.
#define GATHER_LOOP(LOADEXPR)                                        \
  for (int base = 0; base < cnt; base += 64) {                      \
    int e = beg + base + lane;                                      \
    int cv = (e < end) ? cs[e] : 0;                                 \
    int m = cnt - base; if (m > 64) m = 64;                         \
    int j = 0;                                                      \
    for (; j + 8 <= m; j += 8) {                                    \
      _Pragma("unroll")                                             \
      for (int u = 0; u < 8; ++u) {                                 \
        int s = __builtin_amdgcn_readlane(cv, j + u);               \
        LOADEXPR;                                                   \
      }                                                             \
    }                                                               \
    if (j + 4 <= m) {                                               \
      _Pragma("unroll")                                             \
      for (int u = 0; u < 4; ++u) {                                 \
        int s = __builtin_amdgcn_readlane(cv, j + u);               \
        LOADEXPR;                                                   \
      }                                                             \
      j += 4;                                                       \
    }                                                               \
    if (j + 2 <= m) {                                               \
      _Pragma("unroll")                                             \
      for (int u = 0; u < 2; ++u) {                                 \
        int s = __builtin_amdgcn_readlane(cv, j + u);               \
        LOADEXPR;                                                   \
      }                                                             \
      j += 2;                                                       \
    }                                                               \
    if (j < m) {                                                    \
      int s = __builtin_amdgcn_readlane(cv, j);                     \
      LOADEXPR;                                                     \
    }                                                               \
  }

// ---- APPNP iteration (fp8 source): r = 0.8*ni*sum(h8[s]) + 0.2*x0 ----------
template <bool LAST>
__global__ __launch_bounds__(256) void k_appnp8(const unsigned short* __restrict__ h8,
                                                const __half2* __restrict__ x0,
                                                const float* __restrict__ no,
                                                const float* __restrict__ ni,
                                                const int* __restrict__ rp,
                                                const int* __restrict__ cs,
                                                unsigned short* __restrict__ out8,
                                                __half2* __restrict__ out16) {
  int w = (blockIdx.x * 256 + threadIdx.x) >> 6;
  int lane = threadIdx.x & 63;
  if (w >= NN) return;
  const unsigned short* hl = h8 + lane;
  int beg = rp[w], end = rp[w + 1], cnt = end - beg;
  float ax = 0.f, ay = 0.f;
  GATHER_LOOP({
    float2 f = fp8_dec(hl[s * 64]);
    ax += f.x; ay += f.y;
  })
  float wi = 0.8f * ni[w];
  float2 xv = __half22float2(x0[w * 64 + lane]);
  float rx = wi * ax + 0.2f * xv.x;
  float ry = wi * ay + 0.2f * xv.y;
  if (LAST) {
    out16[w * 64 + lane] = __floats2half2_rn(rx, ry);
  } else {
    float sc = no[w];
    out8[w * 64 + lane] = fp8_enc(rx * sc, ry * sc);
  }
}

// packed-store helper: thread (node w, lane) holds features (2*lane, 2*lane+1)
__device__ inline void store_packed(_Float16* __restrict__ zp, int w, int lane,
                                    float v0, float v1) {
  int t = w >> 5, r = w & 31;
  int ks = lane >> 3, g = (lane >> 2) & 1, j = (lane & 3) * 2;
  size_t addr = (((size_t)t * 8 + ks) * 64 + g * 32 + r) * 8 + j;
  *reinterpret_cast<__half2*>(zp + addr) = __floats2half2_rn(v0, v1);
}

// ---- APPNP pass 1 fused with zx-agg: DUAL fp8 gather (4 lines/edge) --------
__global__ __launch_bounds__(256) void k_appnp_first8(const unsigned short* __restrict__ xn8,
                                                      const unsigned short* __restrict__ xp8,
                                                      const __half2* __restrict__ xp,
                                                      const float* __restrict__ epsp,
                                                      const float* __restrict__ no,
                                                      const float* __restrict__ ni,
                                                      const int* __restrict__ rp,
                                                      const int* __restrict__ cs,
                                                      unsigned short* __restrict__ hout8,
                                                      _Float16* __restrict__ zxout) {
  int w = (blockIdx.x * 256 + threadIdx.x) >> 6;
  int lane = threadIdx.x & 63;
  if (w >= NN) return;
  const unsigned short* xnl = xn8 + lane;
  const unsigned short* xpl = xp8 + lane;
  int beg = rp[w], end = rp[w + 1], cnt = end - beg;
  float ax = 0.f, ay = 0.f, bx = 0.f, by = 0.f;
  GATHER_LOOP({
    float2 f = fp8_dec(xnl[s * 64]);
    float2 g2 = fp8_dec(xpl[s * 64]);
    ax += f.x; ay += f.y; bx += g2.x; by += g2.y;
  })
  float2 xv = __half22float2(xp[w * 64 + lane]);
  float wi = 0.8f * ni[w];
  float sc = no[w];
  hout8[w * 64 + lane] = fp8_enc(sc * (wi * ax + 0.2f * xv.x),
                                 sc * (wi * ay + 0.2f * xv.y));
  float e2 = 1.0f + epsp[0];
  store_packed(zxout, w, lane, e2 * xv.x + bx, e2 * xv.y + by);
}

// ---- pair-node half-feature z-gather (fp16, numerics identical) ------------
// Wave = node pair (2wp, 2wp+1); lanes 0-31 own node A's half-row features,
// lanes 32-63 node B's. One load instr serves one edge of EACH node (2 lines)
// -> same lines & instr count as full-row version, but per-launch working set
// halves (12.8 -> 6.4 MB) for higher per-XCD L2 hit rate. Launch per half hf.
__global__ __launch_bounds__(256) void k_gz_pair(const __half2* __restrict__ h,
                                                 const float* __restrict__ epsp,
                                                 const int* __restrict__ rp,
                                                 const int* __restrict__ cs,
                                                 _Float16* __restrict__ zout,
                                                 int hf) {
  int wp = (blockIdx.x * 256 + threadIdx.x) >> 6;
  if (wp >= NN / 2) return;
  int lane = threadIdx.x & 63;
  int l31 = lane & 31;
  int w = wp * 2 + (lane >> 5);
  const __half2* hl = h + hf * 32 + l31;   // row stride 64 half2
  int beg = rp[w], end = rp[w + 1], cnt = end - beg;
  float ax = 0.f, ay = 0.f;
  for (int base = 0;; base += 32) {
    int m = cnt - base;
    if (m > 32) m = 32;
    int mA = __shfl(m, 0), mB = __shfl(m, 32);
    int mmax = mA > mB ? mA : mB;
    if (mmax <= 0) break;
    int cv = (base + l31 < cnt) ? cs[beg + base + l31] : 0;
    int j = 0;
#define PSTEP(U) { int s = __shfl(cv, j + (U), 32);                    \
                   float2 f = __half22float2(hl[(size_t)s * 64]);      \
                   if (j + (U) < m) { ax += f.x; ay += f.y; } }
    for (; j + 8 <= mmax; j += 8) {
      PSTEP(0) PSTEP(1) PSTEP(2) PSTEP(3) PSTEP(4) PSTEP(5) PSTEP(6) PSTEP(7)
    }
    if (j + 4 <= mmax) { PSTEP(0) PSTEP(1) PSTEP(2) PSTEP(3) j += 4; }
    if (j + 2 <= mmax) { PSTEP(0) PSTEP(1) j += 2; }
    if (j < mmax) { PSTEP(0) }
#undef PSTEP
  }
  float e1 = 1.0f + epsp[0];
  float2 hv = __half22float2(h[(size_t)w * 64 + hf * 32 + l31]);
  // packed store at features k0 = hf*64 + l31*2
  int k0 = hf * 64 + l31 * 2;
  int t = w >> 5, r = w & 31;
  int ks = k0 >> 4, g = (k0 >> 3) & 1, jj = k0 & 7;
  size_t addr = (((size_t)t * 8 + ks) * 64 + g * 32 + r) * 8 + jj;
  *reinterpret_cast<__half2*>(zout + addr) =
      __floats2half2_rn(e1 * hv.x + ax, e1 * hv.y + ay);
}

// ---- MFMA GEMM on packed operands: C = Z @ W + b -------------------------
template <int KTOT, bool MISH>
__global__ __launch_bounds__(64) void k_mgemm(const _Float16* __restrict__ z0,
                                              const _Float16* __restrict__ z1,
                                              const _Float16* __restrict__ wp,
                                              const float* __restrict__ bias,
                                              float* __restrict__ outf,
                                              __half2* __restrict__ outh) {
  int lane = threadIdx.x;
  int t = blockIdx.x;
  int row0 = t * 32;
  if (row0 >= NN) return;
  int r31 = lane & 31, g = lane >> 5;
  f32x16 acc[4];
  #pragma unroll
  for (int i = 0; i < 4; ++i) acc[i] = (f32x16)(0.0f);
  #pragma unroll 4
  for (int ks = 0; ks < KTOT / 16; ++ks) {
    const _Float16* zp = (KTOT == 256 && ks >= 8) ? z1 : z0;
    int kls = (KTOT == 256) ? (ks & 7) : ks;
    half8_t a = *reinterpret_cast<const half8_t*>(
        zp + (((size_t)t * 8 + kls) * 64 + lane) * 8);
    #pragma unroll
    for (int nb = 0; nb < 4; ++nb) {
      half8_t b = *reinterpret_cast<const half8_t*>(
          wp + (((size_t)ks * 4 + nb) * 64 + lane) * 8);
      acc[nb] = __builtin_amdgcn_mfma_f32_32x32x16_f16(a, b, acc[nb], 0, 0, 0);
    }
  }
  #pragma unroll
  for (int nb = 0; nb < 4; ++nb) {
    float bv = bias[nb * 32 + r31];
    #pragma unroll
    for (int r = 0; r < 16; ++r) {
      int rl = (r & 3) + 8 * (r >> 2) + 4 * g;
      int grow = row0 + rl;
      if (grow < NN) {
        float v = acc[nb][r] + bv;
        if (MISH) {
          // mish(v) = v*q/(q+2), q = E(E+2), E = e^v
          float E = __expf(v);
          float q = E * (E + 2.f);
          float mv = v * q / (q + 2.f);
          v = (v > 15.f) ? v : mv;
          outf[(size_t)grow * 128 + nb * 32 + r31] = v;
        } else {
          float u = __shfl_xor(v, 1);
          if (!(lane & 1)) {
            outh[((size_t)grow * 128 + nb * 32 + r31) >> 1] = __floats2half2_rn(v, u);
          }
        }
      }
    }
  }
}

extern "C" void kernel_launch(void* const* d_in, const int* in_sizes, int n_in,
                              void* d_out, int out_size, void* d_ws, size_t ws_size,
                              hipStream_t stream) {
  const float* x = (const float*)d_in[0];
  const int* src = (const int*)d_in[1];
  const int* dst = (const int*)d_in[2];
  const float* W1 = (const float*)d_in[3];
  const float* b1 = (const float*)d_in[4];
  const float* W2 = (const float*)d_in[5];
  const float* b2 = (const float*)d_in[6];
  const float* eps1 = (const float*)d_in[7];
  const float* eps2 = (const float*)d_in[8];
  float* out = (float*)d_out;

  char* ws = (char*)d_ws;
  size_t off = 0;
  auto alloc = [&](size_t bytes) -> void* {
    void* p = ws + off;
    off += (bytes + 255) & ~(size_t)255;
    return p;
  };
  const size_t NDP = (size_t)NT * 4096;  // halves per padded fp16 buffer
  __half2* x0h = (__half2*)alloc(NDP * 2);             // tanh(x), fp16
  unsigned short* x0n8 = (unsigned short*)alloc(NDP);  // fp8 tanh(x)*no
  unsigned short* x0p8 = (unsigned short*)alloc(NDP);  // fp8 tanh(x) plain
  unsigned short* hA8 = (unsigned short*)alloc(NDP);   // fp8 APPNP ping
  unsigned short* hB8 = (unsigned short*)alloc(NDP);   // fp8 APPNP pong
  __half2* h5 = (__half2*)alloc(NDP * 2);              // fp16 APPNP output
  __half2* zx = (__half2*)alloc(NDP * 2);              // packed (1+e2)*x0+agg(x0)
  __half2* z1p = (__half2*)alloc(NDP * 2);             // packed (1+e1)*h5+agg(h5)
  __half2* g1h = (__half2*)alloc(NDP * 2);             // GIN1 out, fp16
  __half2* zg = (__half2*)alloc(NDP * 2);              // packed (1+e2)*g1+agg(g1)
  _Float16* w1p = (_Float16*)alloc(128 * 128 * 2);
  _Float16* w2p = (_Float16*)alloc(256 * 128 * 2);
  int* ci = (int*)alloc(NN * 4);
  float* nrm_o = (float*)alloc(NN * 4);
  float* nrm_i = (float*)alloc(NN * 4);
  int* incl = (int*)alloc(NN * 4);
  int* bsum = (int*)alloc(64 * 4);
  int* boff = (int*)alloc(64 * 4);
  int* rp = (int*)alloc((NN + 1) * 4);
  int* lseq = (int*)alloc(NE * 4);
  int* colsrc = (int*)alloc(NE * 4);

  // histogram partials: 2 phases x HB x NBIN2 x 4B = 12.8 MB, aliased over zx
  // (12.8 MB): consumed by k_scatter before zx is first written.
  unsigned int* hpart = (unsigned int*)zx;

  // degrees + per-edge sequence via packed 2-phase LDS histogram
  k_hist2<<<HB, 1024, 0, stream>>>(src, dst, hpart, lseq);
  k_merge2<<<(NBIN2 + 255) / 256, 256, 0, stream>>>(hpart, ci, nrm_o, nrm_i);

  const int SB = (NN + 1023) / 1024;  // 49
  k_scanA<<<SB, 1024, 0, stream>>>(ci, incl, bsum);
  k_scanB<<<1, 64, 0, stream>>>(bsum, boff, SB);
  k_scanC<<<(NN + 255) / 256, 256, 0, stream>>>(incl, ci, boff, rp);
  const int EB = (NE + 255) / 256;
  k_scatter<<<EB, 256, 0, stream>>>(src, dst, lseq, hpart, rp, colsrc);

  k_tanh<<<(NN * 32 + 255) / 256, 256, 0, stream>>>(x, nrm_o, x0h,
                                                    (unsigned int*)x0n8,
                                                    (unsigned int*)x0p8);
  k_wt<<<192, 256, 0, stream>>>(W1, W2, w1p, w2p);

  const int GB = (NN * 64 + 255) / 256;        // one wave per node
  const int GP = (NN / 2 * 64 + 255) / 256;    // one wave per node pair
  // APPNP pass 1 fused with zx-agg (dual fp8 gather) -> hA8, zx(packed)
  k_appnp_first8<<<GB, 256, 0, stream>>>(x0n8, x0p8, x0h, eps2, nrm_o, nrm_i,
                                         rp, colsrc, hA8, (_Float16*)zx);
  // APPNP passes 2..4 (fp8->fp8 scaled), pass 5 (fp8->fp16 unscaled)
  k_appnp8<false><<<GB, 256, 0, stream>>>(hA8, x0h, nrm_o, nrm_i, rp, colsrc,
                                          hB8, nullptr);
  k_appnp8<false><<<GB, 256, 0, stream>>>(hB8, x0h, nrm_o, nrm_i, rp, colsrc,
                                          hA8, nullptr);
  k_appnp8<false><<<GB, 256, 0, stream>>>(hA8, x0h, nrm_o, nrm_i, rp, colsrc,
                                          hB8, nullptr);
  k_appnp8<true><<<GB, 256, 0, stream>>>(hB8, x0h, nrm_o, nrm_i, rp, colsrc,
                                         nullptr, h5);

  // z1(packed) = (1+eps1)*h5 + agg(h5)  [fp16, pair-node half-feature passes]
  k_gz_pair<<<GP, 256, 0, stream>>>(h5, eps1, rp, colsrc, (_Float16*)z1p, 0);
  k_gz_pair<<<GP, 256, 0, stream>>>(h5, eps1, rp, colsrc, (_Float16*)z1p, 1);

  // GIN1: g1 = z1 @ W1 + b1 -> fp16 row-major
  k_mgemm<128, false><<<NT, 64, 0, stream>>>((const _Float16*)z1p, nullptr, w1p, b1,
                                             nullptr, g1h);
  // zg(packed) = (1+eps2)*g1 + agg(g1)  [fp16, pair-node half-feature passes]
  k_gz_pair<<<GP, 256, 0, stream>>>(g1h, eps2, rp, colsrc, (_Float16*)zg, 0);
  k_gz_pair<<<GP, 256, 0, stream>>>(g1h, eps2, rp, colsrc, (_Float16*)zg, 1);
  // GIN2: out = mish([zg | zx] @ W2 + b2)
  k_mgemm<256, true><<<NT, 64, 0, stream>>>((const _Float16*)zg, (const _Float16*)zx,
                                            w2p, b2, out, nullptr);
}